// Round 2
// baseline (3266.299 us; speedup 1.0000x reference)
//
#include <hip/hip_runtime.h>
#include <math.h>

#define D_MODEL 2048
#define HEADS 32
#define HEAD_DIM 64
#define STATE 256
#define KCONV 4
#define CHUNK 64
#define NC 32            // SEQ / CHUNK
#define SEQL 2048
#define BATCHN 2
#define CONV_DIMN 2560   // D_MODEL + 2*STATE
#define PROJ_DIM 4640    // D_MODEL + CONV_DIM + HEADS
#define EPSF 1e-5f
#define BL (BATCHN * SEQL)  // 4096 token rows

// ---------------- RMSNorm (row per block, 2048 cols, 256 threads) ----------
__global__ __launch_bounds__(256) void rmsnorm_k(const float* __restrict__ x,
                                                 const float* __restrict__ w,
                                                 float* __restrict__ out) {
  int row = blockIdx.x;
  int t = threadIdx.x;
  const float4* x4 = (const float4*)(x + (size_t)row * D_MODEL);
  float4 va = x4[t], vb = x4[t + 256];
  float ss = va.x * va.x + va.y * va.y + va.z * va.z + va.w * va.w +
             vb.x * vb.x + vb.y * vb.y + vb.z * vb.z + vb.w * vb.w;
  #pragma unroll
  for (int off = 32; off > 0; off >>= 1) ss += __shfl_down(ss, off);
  __shared__ float ws_[4];
  if ((t & 63) == 0) ws_[t >> 6] = ss;
  __syncthreads();
  float tot = ws_[0] + ws_[1] + ws_[2] + ws_[3];
  float scale = rsqrtf(tot / (float)D_MODEL + EPSF);
  const float4* w4 = (const float4*)w;
  float4 wa = w4[t], wb = w4[t + 256];
  float4* o4 = (float4*)(out + (size_t)row * D_MODEL);
  float4 oa, ob;
  oa.x = va.x * scale * wa.x; oa.y = va.y * scale * wa.y;
  oa.z = va.z * scale * wa.z; oa.w = va.w * scale * wa.w;
  ob.x = vb.x * scale * wb.x; ob.y = vb.y * scale * wb.y;
  ob.z = vb.z * scale * wb.z; ob.w = vb.w * scale * wb.w;
  o4[t] = oa; o4[t + 256] = ob;
}

// ---------------- fp32 SGEMM: C[M,N] = A[M,K] @ B[K,N], row-major ----------
// 64x64 tile, BK=16, 256 threads, 4x4 per thread. M%64==0, K%16==0 assumed.
__global__ __launch_bounds__(256) void sgemm_k(const float* __restrict__ A,
                                               const float* __restrict__ B,
                                               float* __restrict__ C,
                                               int M, int N, int K) {
  __shared__ float sA[16][64];
  __shared__ float sB[16][64];
  int tid = threadIdx.x;
  int m0 = blockIdx.y * 64;
  int n0 = blockIdx.x * 64;
  int tm = (tid & 15) * 4;
  int tn = (tid >> 4) * 4;
  int la_m = tid >> 2;           // 0..63
  int la_k = (tid & 3) * 4;      // 0,4,8,12
  int lb_k = tid >> 4;           // 0..15
  int lb_n = (tid & 15) * 4;     // 0..60
  bool nfull = (n0 + 64 <= N);
  float acc[4][4] = {};
  const float* Arow = A + (size_t)(m0 + la_m) * K + la_k;
  for (int k0 = 0; k0 < K; k0 += 16) {
    __syncthreads();
    float4 av = *(const float4*)(Arow + k0);
    sA[la_k + 0][la_m] = av.x;
    sA[la_k + 1][la_m] = av.y;
    sA[la_k + 2][la_m] = av.z;
    sA[la_k + 3][la_m] = av.w;
    const float* Bp = B + (size_t)(k0 + lb_k) * N + n0 + lb_n;
    if (nfull) {
      float4 bv = *(const float4*)Bp;
      sB[lb_k][lb_n + 0] = bv.x; sB[lb_k][lb_n + 1] = bv.y;
      sB[lb_k][lb_n + 2] = bv.z; sB[lb_k][lb_n + 3] = bv.w;
    } else {
      #pragma unroll
      for (int i = 0; i < 4; i++)
        sB[lb_k][lb_n + i] = (n0 + lb_n + i < N) ? Bp[i] : 0.f;
    }
    __syncthreads();
    #pragma unroll
    for (int k = 0; k < 16; k++) {
      float a0 = sA[k][tm], a1 = sA[k][tm + 1], a2 = sA[k][tm + 2], a3 = sA[k][tm + 3];
      float b0 = sB[k][tn], b1 = sB[k][tn + 1], b2 = sB[k][tn + 2], b3 = sB[k][tn + 3];
      acc[0][0] += a0 * b0; acc[0][1] += a0 * b1; acc[0][2] += a0 * b2; acc[0][3] += a0 * b3;
      acc[1][0] += a1 * b0; acc[1][1] += a1 * b1; acc[1][2] += a1 * b2; acc[1][3] += a1 * b3;
      acc[2][0] += a2 * b0; acc[2][1] += a2 * b1; acc[2][2] += a2 * b2; acc[2][3] += a2 * b3;
      acc[3][0] += a3 * b0; acc[3][1] += a3 * b1; acc[3][2] += a3 * b2; acc[3][3] += a3 * b3;
    }
  }
  #pragma unroll
  for (int i = 0; i < 4; i++) {
    int m = m0 + tm + i;
    #pragma unroll
    for (int j = 0; j < 4; j++) {
      int n = n0 + tn + j;
      if (n < N) C[(size_t)m * N + n] = acc[i][j];
    }
  }
}

// ---------------- depthwise causal conv (K=4) + bias + SiLU ----------------
__global__ __launch_bounds__(256) void conv_silu_k(const float* __restrict__ proj,
                                                   const float* __restrict__ cw,
                                                   const float* __restrict__ cb,
                                                   float* __restrict__ out) {
  int idx = blockIdx.x * 256 + threadIdx.x;   // BL * CONV_DIM total
  int c = idx % CONV_DIMN;
  int bt = idx / CONV_DIMN;
  int t = bt % SEQL;
  int b = bt / SEQL;
  float acc = cb[c];
  #pragma unroll
  for (int k = 0; k < KCONV; k++) {
    int tt = t - (KCONV - 1) + k;
    if (tt >= 0)
      acc += proj[((size_t)(b * SEQL + tt)) * PROJ_DIM + D_MODEL + c] * cw[c * KCONV + k];
  }
  out[idx] = acc / (1.f + expf(-acc));
}

// ---------------- dt softplus + per-chunk cumsum of A*dt -------------------
__global__ void dt_acs_k(const float* __restrict__ proj,
                         const float* __restrict__ dt_bias,
                         const float* __restrict__ A_log,
                         float* __restrict__ dtb, float* __restrict__ acsb) {
  int bc = blockIdx.x;
  int b = bc / NC, c = bc % NC;
  int l = threadIdx.x;  // 0..63
  int tok = c * CHUNK + l;
  size_t base = ((size_t)(b * SEQL + tok)) * HEADS;
  size_t pbase = ((size_t)(b * SEQL + tok)) * PROJ_DIM + (D_MODEL + CONV_DIMN);
  for (int h = 0; h < HEADS; h++) {
    float raw = proj[pbase + h] + dt_bias[h];
    float dt = raw > 20.f ? raw : log1pf(expf(raw));
    float adt = -expf(A_log[h]) * dt;
    float cs = adt;
    #pragma unroll
    for (int off = 1; off < 64; off <<= 1) {
      float v = __shfl_up(cs, off);
      if (l >= off) cs += v;
    }
    dtb[base + h] = dt;
    acsb[base + h] = cs;
  }
}

// ---------------- CB[b,c,l,s] = sum_n C(l,n) * B(s,n) ----------------------
__global__ __launch_bounds__(256) void cb_k(const float* __restrict__ conv,
                                            float* __restrict__ CB) {
  int bc = blockIdx.x;
  int b = bc / NC, c = bc % NC;
  __shared__ float sC[64][65];
  __shared__ float sB[64][65];
  int t = threadIdx.x;
  int s = t & 63;
  int lb = (t >> 6) * 16;
  float acc[16] = {};
  size_t rowbase = ((size_t)(b * SEQL + c * CHUNK)) * CONV_DIMN;
  for (int nt = 0; nt < 4; nt++) {
    __syncthreads();
    #pragma unroll
    for (int i = 0; i < 16; i++) {
      int e = t + 256 * i;
      int r = e >> 6, col = e & 63;
      sC[r][col] = conv[rowbase + (size_t)r * CONV_DIMN + (D_MODEL + STATE) + nt * 64 + col];
      sB[r][col] = conv[rowbase + (size_t)r * CONV_DIMN + D_MODEL + nt * 64 + col];
    }
    __syncthreads();
    for (int n = 0; n < 64; n++) {
      float bv = sB[s][n];
      #pragma unroll
      for (int j = 0; j < 16; j++) acc[j] += sC[lb + j][n] * bv;
    }
  }
  size_t ob = ((size_t)bc) * 64 * 64;
  #pragma unroll
  for (int j = 0; j < 16; j++) CB[ob + (size_t)(lb + j) * 64 + s] = acc[j];
}

// ---------------- Y_diag + D*xs (writes Y) ---------------------------------
__global__ __launch_bounds__(256) void ydiag_k(const float* __restrict__ conv,
                                               const float* __restrict__ CB,
                                               const float* __restrict__ dtb,
                                               const float* __restrict__ acsb,
                                               const float* __restrict__ D_skip,
                                               float* __restrict__ Y) {
  int blk = blockIdx.x;            // ((b*NC)+c)*HEADS + h
  int h = blk & 31, c = (blk >> 5) & 31, b = blk >> 10;
  __shared__ float buf1[64][65];   // xs(l,p)
  __shared__ float buf2[64][65];   // CB -> M(l,s)
  __shared__ float sdt[64], sacs[64];
  int t = threadIdx.x;
  int p = t & 63;
  int lb = (t >> 6) * 16;
  size_t rowbase = ((size_t)(b * SEQL + c * CHUNK)) * CONV_DIMN;
  size_t ab = ((size_t)(b * SEQL + c * CHUNK)) * HEADS;
  size_t cbbase = ((size_t)(b * NC + c)) * 64 * 64;
  #pragma unroll
  for (int i = 0; i < 16; i++) {
    int e = t + 256 * i;
    int r = e >> 6, col = e & 63;
    buf1[r][col] = conv[rowbase + (size_t)r * CONV_DIMN + h * HEAD_DIM + col];
    buf2[r][col] = CB[cbbase + (size_t)r * 64 + col];
  }
  if (t < 64) {
    sacs[t] = acsb[ab + (size_t)t * HEADS + h];
    sdt[t] = dtb[ab + (size_t)t * HEADS + h];
  }
  __syncthreads();
  // in-place: CB -> M(l,s) = CB * exp(acs_l - acs_s) * dt_s * [s<=l]
  #pragma unroll
  for (int i = 0; i < 16; i++) {
    int e = t + 256 * i;
    int r = e >> 6, col = e & 63;  // r=l, col=s
    float m = 0.f;
    if (col <= r) m = buf2[r][col] * expf(sacs[r] - sacs[col]) * sdt[col];
    buf2[r][col] = m;
  }
  __syncthreads();
  float acc[16];
  float dsk = D_skip[h];
  #pragma unroll
  for (int j = 0; j < 16; j++) acc[j] = dsk * buf1[lb + j][p];
  for (int s = 0; s < 64; s++) {
    float xv = buf1[s][p];
    #pragma unroll
    for (int j = 0; j < 16; j++) acc[j] += buf2[lb + j][s] * xv;
  }
  size_t ybase = ((size_t)(b * SEQL + c * CHUNK)) * D_MODEL + h * HEAD_DIM;
  #pragma unroll
  for (int j = 0; j < 16; j++) Y[ybase + (size_t)(lb + j) * D_MODEL + p] = acc[j];
}

// ---------------- fused sequential scan + Y_off (Y +=) ---------------------
// grid: ((b*HEADS)+h)*4 + pg, 256 blocks; block owns S[16p x 256n] in LDS,
// iterates chunks 0..31 sequentially. No states buffer in global memory.
__global__ __launch_bounds__(256) void scan_yoff_k(const float* __restrict__ conv,
                                                   const float* __restrict__ dtb,
                                                   const float* __restrict__ acsb,
                                                   float* __restrict__ Y) {
  int pg = blockIdx.x & 3;
  int h = (blockIdx.x >> 2) & 31;
  int b = blockIdx.x >> 7;
  int t = threadIdx.x;
  __shared__ float S[16][260];     // running state slice S[p'][n], padded
  __shared__ float buf[64][68];    // staged C*e^acs or B*w tile (l x 64n)
  __shared__ float sxs[64][16];    // xs(l, block's 16 p)
  __shared__ float swt[64];        // exp(acs_last - acs_l) * dt_l
  __shared__ float sea[64];        // exp(acs_l)
  __shared__ float sdec[1];        // exp(acs_last)
  for (int i = t; i < 16 * 260; i += 256) ((float*)S)[i] = 0.f;

  int tl = t & 63, tpg = t >> 6;       // Y_off mapping: row l=tl, p' = tpg*4+j
  int p2 = t >> 4, n2 = (t & 15) * 4;  // update mapping: p'=p2, n = nt*64+n2

  for (int c = 0; c < NC; c++) {
    size_t rowbase = ((size_t)(b * SEQL + c * CHUNK)) * CONV_DIMN;
    size_t ab = ((size_t)(b * SEQL + c * CHUNK)) * HEADS;
    // stage xs slice + per-chunk scalars
    {
      int l = t >> 2, i0 = (t & 3) * 4;
      float4 v = *(const float4*)&conv[rowbase + (size_t)l * CONV_DIMN + h * HEAD_DIM + pg * 16 + i0];
      sxs[l][i0 + 0] = v.x; sxs[l][i0 + 1] = v.y;
      sxs[l][i0 + 2] = v.z; sxs[l][i0 + 3] = v.w;
    }
    if (t < 64) {
      float a = acsb[ab + (size_t)t * HEADS + h];
      float alast = acsb[ab + (size_t)63 * HEADS + h];
      swt[t] = expf(alast - a) * dtb[ab + (size_t)t * HEADS + h];
      sea[t] = expf(a);
      if (t == 63) sdec[0] = expf(alast);
    }
    __syncthreads();

    // ---- Y_off with current (prev) S ----
    float acc[4] = {0.f, 0.f, 0.f, 0.f};
    for (int nt = 0; nt < 4; nt++) {
      #pragma unroll
      for (int i = 0; i < 16; i++) {
        int e = t + 256 * i;
        int r = e >> 6, col = e & 63;
        buf[r][col] = conv[rowbase + (size_t)r * CONV_DIMN + (D_MODEL + STATE) + nt * 64 + col] * sea[r];
      }
      __syncthreads();
      #pragma unroll 4
      for (int n = 0; n < 64; n += 4) {
        float4 cv = *(const float4*)&buf[tl][n];
        float4 s0 = *(const float4*)&S[tpg * 4 + 0][nt * 64 + n];
        float4 s1 = *(const float4*)&S[tpg * 4 + 1][nt * 64 + n];
        float4 s2 = *(const float4*)&S[tpg * 4 + 2][nt * 64 + n];
        float4 s3 = *(const float4*)&S[tpg * 4 + 3][nt * 64 + n];
        acc[0] += cv.x * s0.x + cv.y * s0.y + cv.z * s0.z + cv.w * s0.w;
        acc[1] += cv.x * s1.x + cv.y * s1.y + cv.z * s1.z + cv.w * s1.w;
        acc[2] += cv.x * s2.x + cv.y * s2.y + cv.z * s2.z + cv.w * s2.w;
        acc[3] += cv.x * s3.x + cv.y * s3.y + cv.z * s3.z + cv.w * s3.w;
      }
      __syncthreads();
    }
    // Y += Y_off  (disjoint 16-float column slice per block -> race-free)
    {
      size_t yi = ((size_t)(b * SEQL + c * CHUNK + tl)) * D_MODEL + h * HEAD_DIM + pg * 16 + tpg * 4;
      float4* yp = (float4*)&Y[yi];
      float4 yv = *yp;
      yv.x += acc[0]; yv.y += acc[1]; yv.z += acc[2]; yv.w += acc[3];
      *yp = yv;
    }

    // ---- state update: S = S*dec + sum_l B(l,n)*swt(l)*xs(l,p) ----
    for (int nt = 0; nt < 4; nt++) {
      #pragma unroll
      for (int i = 0; i < 16; i++) {
        int e = t + 256 * i;
        int r = e >> 6, col = e & 63;
        buf[r][col] = conv[rowbase + (size_t)r * CONV_DIMN + D_MODEL + nt * 64 + col] * swt[r];
      }
      __syncthreads();
      float4 ns = {0.f, 0.f, 0.f, 0.f};
      #pragma unroll 4
      for (int l = 0; l < 64; l++) {
        float xw = sxs[l][p2];
        float4 bv = *(const float4*)&buf[l][n2];
        ns.x += bv.x * xw; ns.y += bv.y * xw;
        ns.z += bv.z * xw; ns.w += bv.w * xw;
      }
      float dec = sdec[0];
      float4 sv = *(const float4*)&S[p2][nt * 64 + n2];
      sv.x = sv.x * dec + ns.x; sv.y = sv.y * dec + ns.y;
      sv.z = sv.z * dec + ns.z; sv.w = sv.w * dec + ns.w;
      *(float4*)&S[p2][nt * 64 + n2] = sv;
      __syncthreads();
    }
  }
}

// ---------------- gated RMSNorm: y = rmsnorm(Y * silu(z)) * gw, in-place ---
__global__ __launch_bounds__(256) void gated_norm_k(float* __restrict__ Y,
                                                    const float* __restrict__ proj,
                                                    const float* __restrict__ gw) {
  int row = blockIdx.x;
  int t = threadIdx.x;
  float4* y4 = (float4*)(Y + (size_t)row * D_MODEL);
  const float4* z4 = (const float4*)(proj + (size_t)row * PROJ_DIM);
  float4 ya = y4[t], yb = y4[t + 256];
  float4 za = z4[t], zb = z4[t + 256];
  float4 ga, gb;
  ga.x = ya.x * (za.x / (1.f + expf(-za.x)));
  ga.y = ya.y * (za.y / (1.f + expf(-za.y)));
  ga.z = ya.z * (za.z / (1.f + expf(-za.z)));
  ga.w = ya.w * (za.w / (1.f + expf(-za.w)));
  gb.x = yb.x * (zb.x / (1.f + expf(-zb.x)));
  gb.y = yb.y * (zb.y / (1.f + expf(-zb.y)));
  gb.z = yb.z * (zb.z / (1.f + expf(-zb.z)));
  gb.w = yb.w * (zb.w / (1.f + expf(-zb.w)));
  float ss = ga.x * ga.x + ga.y * ga.y + ga.z * ga.z + ga.w * ga.w +
             gb.x * gb.x + gb.y * gb.y + gb.z * gb.z + gb.w * gb.w;
  #pragma unroll
  for (int off = 32; off > 0; off >>= 1) ss += __shfl_down(ss, off);
  __shared__ float ws_[4];
  if ((t & 63) == 0) ws_[t >> 6] = ss;
  __syncthreads();
  float tot = ws_[0] + ws_[1] + ws_[2] + ws_[3];
  float scale = rsqrtf(tot / (float)D_MODEL + EPSF);
  const float4* g4 = (const float4*)gw;
  float4 wa = g4[t], wb = g4[t + 256];
  ga.x *= scale * wa.x; ga.y *= scale * wa.y; ga.z *= scale * wa.z; ga.w *= scale * wa.w;
  gb.x *= scale * wb.x; gb.y *= scale * wb.y; gb.z *= scale * wb.z; gb.w *= scale * wb.w;
  y4[t] = ga; y4[t + 256] = gb;
}

extern "C" void kernel_launch(void* const* d_in, const int* in_sizes, int n_in,
                              void* d_out, int out_size, void* d_ws, size_t ws_size,
                              hipStream_t stream) {
  const float* x       = (const float*)d_in[0];
  const float* norm_w  = (const float*)d_in[1];
  const float* w_in    = (const float*)d_in[2];
  const float* conv_w  = (const float*)d_in[3];
  const float* conv_b  = (const float*)d_in[4];
  const float* dt_bias = (const float*)d_in[5];
  const float* A_log   = (const float*)d_in[6];
  const float* D_skip  = (const float*)d_in[7];
  const float* gnorm_w = (const float*)d_in[8];
  const float* w_out   = (const float*)d_in[9];
  const float* wo_w    = (const float*)d_in[10];
  float* out = (float*)d_out;

  // workspace layout (floats): 38,404,096 floats = 146.5 MiB total
  float* ws   = (float*)d_ws;
  float* xn   = ws;                    // 8,388,608  (xn; later reused as Y)
  float* proj = xn + 8388608;          // 19,005,440 (z live until gated_norm)
  float* conv = proj + 19005440;       // 10,485,760 (later reused as t1)
  float* dtb  = conv + 10485760;       //    131,072
  float* acsb = dtb + 131072;          //    131,072
  float* CBb  = acsb + 131072;         //    262,144
  float* Yb = xn;     // xn dead after proj GEMM
  float* t1 = conv;   // conv dead after scan_yoff_k

  rmsnorm_k<<<BL, 256, 0, stream>>>(x, norm_w, xn);
  sgemm_k<<<dim3((PROJ_DIM + 63) / 64, BL / 64), 256, 0, stream>>>(xn, w_in, proj, BL, PROJ_DIM, D_MODEL);
  conv_silu_k<<<(BL * CONV_DIMN) / 256, 256, 0, stream>>>(proj, conv_w, conv_b, conv);
  dt_acs_k<<<BATCHN * NC, 64, 0, stream>>>(proj, dt_bias, A_log, dtb, acsb);
  cb_k<<<BATCHN * NC, 256, 0, stream>>>(conv, CBb);
  ydiag_k<<<BATCHN * NC * HEADS, 256, 0, stream>>>(conv, CBb, dtb, acsb, D_skip, Yb);
  scan_yoff_k<<<BATCHN * HEADS * 4, 256, 0, stream>>>(conv, dtb, acsb, Yb);
  gated_norm_k<<<BL, 256, 0, stream>>>(Yb, proj, gnorm_w);
  sgemm_k<<<dim3(D_MODEL / 64, BL / 64), 256, 0, stream>>>(Yb, w_out, t1, BL, D_MODEL, D_MODEL);
  sgemm_k<<<dim3(D_MODEL / 64, BL / 64), 256, 0, stream>>>(t1, wo_w, out, BL, D_MODEL, D_MODEL);
}

// Round 3
// 1544.928 us; speedup vs baseline: 2.1142x; 2.1142x over previous
//
#include <hip/hip_runtime.h>
#include <math.h>

#define D_MODEL 2048
#define HEADS 32
#define HEAD_DIM 64
#define STATE 256
#define KCONV 4
#define CHUNK 64
#define NC 32            // SEQ / CHUNK
#define SEQL 2048
#define BATCHN 2
#define CONV_DIMN 2560   // D_MODEL + 2*STATE
#define PROJ_DIM 4640    // D_MODEL + CONV_DIM + HEADS
#define NPAD_IN 4736     // 37*128, zero-padded rows in w_inT
#define EPSF 1e-5f
#define BL (BATCHN * SEQL)  // 4096 token rows

typedef __attribute__((ext_vector_type(8))) short short8;
typedef __attribute__((ext_vector_type(4))) float f32x4;

__device__ __forceinline__ short f2bf(float f) {
  unsigned u = __builtin_bit_cast(unsigned, f);
  u = (u + 0x7fffu + ((u >> 16) & 1u)) >> 16;   // RNE
  return (short)u;
}

__device__ __forceinline__ void gld16(const void* g, void* l) {
  __builtin_amdgcn_global_load_lds((const __attribute__((address_space(1))) unsigned int*)g,
                                   (__attribute__((address_space(3))) unsigned int*)l,
                                   16, 0, 0);
}

// ---------------- RMSNorm -> bf16 (row per block, 2048 cols) ---------------
__global__ __launch_bounds__(256) void rmsnorm_bf16_k(const float* __restrict__ x,
                                                      const float* __restrict__ w,
                                                      short* __restrict__ out) {
  int row = blockIdx.x;
  int t = threadIdx.x;
  const float4* x4 = (const float4*)(x + (size_t)row * D_MODEL);
  float4 va = x4[2 * t], vb = x4[2 * t + 1];
  float ss = va.x * va.x + va.y * va.y + va.z * va.z + va.w * va.w +
             vb.x * vb.x + vb.y * vb.y + vb.z * vb.z + vb.w * vb.w;
  #pragma unroll
  for (int off = 32; off > 0; off >>= 1) ss += __shfl_down(ss, off);
  __shared__ float ws_[4];
  if ((t & 63) == 0) ws_[t >> 6] = ss;
  __syncthreads();
  float tot = ws_[0] + ws_[1] + ws_[2] + ws_[3];
  float scale = rsqrtf(tot / (float)D_MODEL + EPSF);
  const float4* w4 = (const float4*)w;
  float4 wa = w4[2 * t], wb = w4[2 * t + 1];
  short tmp[8];
  tmp[0] = f2bf(va.x * scale * wa.x); tmp[1] = f2bf(va.y * scale * wa.y);
  tmp[2] = f2bf(va.z * scale * wa.z); tmp[3] = f2bf(va.w * scale * wa.w);
  tmp[4] = f2bf(vb.x * scale * wb.x); tmp[5] = f2bf(vb.y * scale * wb.y);
  tmp[6] = f2bf(vb.z * scale * wb.z); tmp[7] = f2bf(vb.w * scale * wb.w);
  *(int4*)(out + (size_t)row * D_MODEL + t * 8) = *(int4*)tmp;
}

// ---------------- transpose + fp32->bf16: W[K,N] -> WT[Npad,K] -------------
__global__ __launch_bounds__(256) void transpose_bf16_k(const float* __restrict__ W,
                                                        short* __restrict__ WT,
                                                        int K, int N, int Npad) {
  __shared__ float tile[32][33];
  int bn = blockIdx.x * 32, bk = blockIdx.y * 32;
  int tx = threadIdx.x & 31, ty = threadIdx.x >> 5;  // ty 0..7
  #pragma unroll
  for (int i = 0; i < 32; i += 8) {
    int k = bk + ty + i, n = bn + tx;
    tile[ty + i][tx] = (n < N) ? W[(size_t)k * N + n] : 0.f;
  }
  __syncthreads();
  #pragma unroll
  for (int i = 0; i < 32; i += 8) {
    int n = bn + ty + i, k = bk + tx;
    WT[(size_t)n * K + k] = f2bf(tile[tx][ty + i]);
  }
}

// ---------------- fp32 dt head-projection: dtraw[row,h] --------------------
__global__ __launch_bounds__(256) void dt_gemm_k(const float* __restrict__ x,
                                                 const float* __restrict__ norm_w,
                                                 const float* __restrict__ w_in,
                                                 float* __restrict__ dtraw) {
  int row = blockIdx.x;
  int t = threadIdx.x;
  __shared__ float sx[D_MODEL];
  __shared__ float red[8][32];
  __shared__ float sred[4];
  const float4* x4 = (const float4*)(x + (size_t)row * D_MODEL);
  const float4* nw4 = (const float4*)norm_w;
  float ss = 0.f;
  for (int i = t; i < D_MODEL / 4; i += 256) {
    float4 v = x4[i];
    ss += v.x * v.x + v.y * v.y + v.z * v.z + v.w * v.w;
    float4 nw = nw4[i];
    float4 pv; pv.x = v.x * nw.x; pv.y = v.y * nw.y; pv.z = v.z * nw.z; pv.w = v.w * nw.w;
    ((float4*)sx)[i] = pv;
  }
  #pragma unroll
  for (int off = 32; off > 0; off >>= 1) ss += __shfl_down(ss, off);
  if ((t & 63) == 0) sred[t >> 6] = ss;
  __syncthreads();
  float tot = sred[0] + sred[1] + sred[2] + sred[3];
  float scale = rsqrtf(tot / (float)D_MODEL + EPSF);
  int h = t & 31, sl = t >> 5;
  float acc = 0.f;
  for (int k = sl * 256; k < sl * 256 + 256; k++)
    acc += sx[k] * w_in[(size_t)k * PROJ_DIM + (D_MODEL + CONV_DIMN) + h];
  red[sl][h] = acc;
  __syncthreads();
  if (t < 32) {
    float s = 0.f;
    #pragma unroll
    for (int i = 0; i < 8; i++) s += red[i][t];
    dtraw[(size_t)row * HEADS + t] = s * scale;
  }
}

// ---------------- bf16 MFMA GEMM: C[M,N] = A[M,K] @ BT[Npad,K]^T -----------
// 128x128 tile, BK=32, 256 thr = 4 waves (2x2), 16x16x32 MFMA, 4x4 tiles/wave.
// global_load_lds width-16 staging; XOR k-slot swizzle keeps frag reads 2-way.
template<bool BF16OUT>
__global__ __launch_bounds__(256) void gemm_bt_k(const short* __restrict__ A,
                                                 const short* __restrict__ BT,
                                                 void* __restrict__ Cout,
                                                 int M, int N, int K) {
  __shared__ short sA[4096];   // 128 rows x 32 bf16, k-slots XOR-swizzled
  __shared__ short sB[4096];
  int t = threadIdx.x;
  int lane = t & 63, w = t >> 6;
  int m0 = blockIdx.y * 128, n0 = blockIdx.x * 128;
  f32x4 acc[4][4] = {};
  int rS[2], ksS[2];
  #pragma unroll
  for (int ld = 0; ld < 2; ld++) {
    int c = w + ld * 4;
    int r = c * 16 + (lane >> 2);
    rS[ld] = r;
    ksS[ld] = (((lane & 3) ^ ((r >> 1) & 3))) * 8;
  }
  int q = lane >> 4, mr = lane & 15;
  int wm = (w & 1) * 64, wn = (w >> 1) * 64;
  int aoff[4], boff[4];
  #pragma unroll
  for (int i = 0; i < 4; i++) {
    int r = wm + i * 16 + mr;
    aoff[i] = r * 32 + (q ^ ((r >> 1) & 3)) * 8;
    int rn = wn + i * 16 + mr;
    boff[i] = rn * 32 + (q ^ ((rn >> 1) & 3)) * 8;
  }
  for (int k0 = 0; k0 < K; k0 += 32) {
    __syncthreads();
    #pragma unroll
    for (int ld = 0; ld < 2; ld++) {
      int c = w + ld * 4;
      gld16(A + (size_t)(m0 + rS[ld]) * K + k0 + ksS[ld], &sA[c * 512]);
      gld16(BT + (size_t)(n0 + rS[ld]) * K + k0 + ksS[ld], &sB[c * 512]);
    }
    __syncthreads();
    short8 af[4], bfr[4];
    #pragma unroll
    for (int i = 0; i < 4; i++) af[i] = *(const short8*)&sA[aoff[i]];
    #pragma unroll
    for (int i = 0; i < 4; i++) bfr[i] = *(const short8*)&sB[boff[i]];
    #pragma unroll
    for (int mi = 0; mi < 4; mi++)
      #pragma unroll
      for (int ni = 0; ni < 4; ni++)
        acc[mi][ni] = __builtin_amdgcn_mfma_f32_16x16x32_bf16(af[mi], bfr[ni], acc[mi][ni], 0, 0, 0);
  }
  int orow = (lane >> 4) * 4, ocol = lane & 15;
  #pragma unroll
  for (int mi = 0; mi < 4; mi++) {
    #pragma unroll
    for (int ni = 0; ni < 4; ni++) {
      int gn = n0 + wn + ni * 16 + ocol;
      if (gn >= N) continue;
      #pragma unroll
      for (int r = 0; r < 4; r++) {
        int gm = m0 + wm + mi * 16 + orow + r;
        if (BF16OUT) ((short*)Cout)[(size_t)gm * N + gn] = f2bf(acc[mi][ni][r]);
        else         ((float*)Cout)[(size_t)gm * N + gn] = acc[mi][ni][r];
      }
    }
  }
}

// ---------------- depthwise causal conv (K=4) + bias + SiLU ----------------
__global__ __launch_bounds__(256) void conv_silu_k(const float* __restrict__ proj,
                                                   const float* __restrict__ cw,
                                                   const float* __restrict__ cb,
                                                   float* __restrict__ out) {
  int idx = blockIdx.x * 256 + threadIdx.x;   // BL * CONV_DIM total
  int c = idx % CONV_DIMN;
  int bt = idx / CONV_DIMN;
  int t = bt % SEQL;
  int b = bt / SEQL;
  float acc = cb[c];
  #pragma unroll
  for (int k = 0; k < KCONV; k++) {
    int tt = t - (KCONV - 1) + k;
    if (tt >= 0)
      acc += proj[((size_t)(b * SEQL + tt)) * PROJ_DIM + D_MODEL + c] * cw[c * KCONV + k];
  }
  out[idx] = acc / (1.f + expf(-acc));
}

// ---------------- dt softplus + per-chunk cumsum of A*dt -------------------
__global__ void dt_acs_k(const float* __restrict__ dtraw,
                         const float* __restrict__ dt_bias,
                         const float* __restrict__ A_log,
                         float* __restrict__ dtb, float* __restrict__ acsb) {
  int bc = blockIdx.x;
  int b = bc / NC, c = bc % NC;
  int l = threadIdx.x;  // 0..63
  int tok = c * CHUNK + l;
  size_t base = ((size_t)(b * SEQL + tok)) * HEADS;
  for (int h = 0; h < HEADS; h++) {
    float raw = dtraw[base + h] + dt_bias[h];
    float dt = raw > 20.f ? raw : log1pf(expf(raw));
    float adt = -expf(A_log[h]) * dt;
    float cs = adt;
    #pragma unroll
    for (int off = 1; off < 64; off <<= 1) {
      float v = __shfl_up(cs, off);
      if (l >= off) cs += v;
    }
    dtb[base + h] = dt;
    acsb[base + h] = cs;
  }
}

// ---------------- CB[b,c,l,s] = sum_n C(l,n) * B(s,n) ----------------------
__global__ __launch_bounds__(256) void cb_k(const float* __restrict__ conv,
                                            float* __restrict__ CB) {
  int bc = blockIdx.x;
  int b = bc / NC, c = bc % NC;
  __shared__ float sC[64][65];
  __shared__ float sB[64][65];
  int t = threadIdx.x;
  int s = t & 63;
  int lb = (t >> 6) * 16;
  float acc[16] = {};
  size_t rowbase = ((size_t)(b * SEQL + c * CHUNK)) * CONV_DIMN;
  for (int nt = 0; nt < 4; nt++) {
    __syncthreads();
    #pragma unroll
    for (int i = 0; i < 16; i++) {
      int e = t + 256 * i;
      int r = e >> 6, col = e & 63;
      sC[r][col] = conv[rowbase + (size_t)r * CONV_DIMN + (D_MODEL + STATE) + nt * 64 + col];
      sB[r][col] = conv[rowbase + (size_t)r * CONV_DIMN + D_MODEL + nt * 64 + col];
    }
    __syncthreads();
    for (int n = 0; n < 64; n++) {
      float bv = sB[s][n];
      #pragma unroll
      for (int j = 0; j < 16; j++) acc[j] += sC[lb + j][n] * bv;
    }
  }
  size_t ob = ((size_t)bc) * 64 * 64;
  #pragma unroll
  for (int j = 0; j < 16; j++) CB[ob + (size_t)(lb + j) * 64 + s] = acc[j];
}

// ---------------- Y_diag + D*xs (writes Y) ---------------------------------
__global__ __launch_bounds__(256) void ydiag_k(const float* __restrict__ conv,
                                               const float* __restrict__ CB,
                                               const float* __restrict__ dtb,
                                               const float* __restrict__ acsb,
                                               const float* __restrict__ D_skip,
                                               float* __restrict__ Y) {
  int blk = blockIdx.x;            // ((b*NC)+c)*HEADS + h
  int h = blk & 31, c = (blk >> 5) & 31, b = blk >> 10;
  __shared__ float buf1[64][65];   // xs(l,p)
  __shared__ float buf2[64][65];   // CB -> M(l,s)
  __shared__ float sdt[64], sacs[64];
  int t = threadIdx.x;
  int p = t & 63;
  int lb = (t >> 6) * 16;
  size_t rowbase = ((size_t)(b * SEQL + c * CHUNK)) * CONV_DIMN;
  size_t ab = ((size_t)(b * SEQL + c * CHUNK)) * HEADS;
  size_t cbbase = ((size_t)(b * NC + c)) * 64 * 64;
  #pragma unroll
  for (int i = 0; i < 16; i++) {
    int e = t + 256 * i;
    int r = e >> 6, col = e & 63;
    buf1[r][col] = conv[rowbase + (size_t)r * CONV_DIMN + h * HEAD_DIM + col];
    buf2[r][col] = CB[cbbase + (size_t)r * 64 + col];
  }
  if (t < 64) {
    sacs[t] = acsb[ab + (size_t)t * HEADS + h];
    sdt[t] = dtb[ab + (size_t)t * HEADS + h];
  }
  __syncthreads();
  #pragma unroll
  for (int i = 0; i < 16; i++) {
    int e = t + 256 * i;
    int r = e >> 6, col = e & 63;  // r=l, col=s
    float m = 0.f;
    if (col <= r) m = buf2[r][col] * expf(sacs[r] - sacs[col]) * sdt[col];
    buf2[r][col] = m;
  }
  __syncthreads();
  float acc[16];
  float dsk = D_skip[h];
  #pragma unroll
  for (int j = 0; j < 16; j++) acc[j] = dsk * buf1[lb + j][p];
  for (int s = 0; s < 64; s++) {
    float xv = buf1[s][p];
    #pragma unroll
    for (int j = 0; j < 16; j++) acc[j] += buf2[lb + j][s] * xv;
  }
  size_t ybase = ((size_t)(b * SEQL + c * CHUNK)) * D_MODEL + h * HEAD_DIM;
  #pragma unroll
  for (int j = 0; j < 16; j++) Y[ybase + (size_t)(lb + j) * D_MODEL + p] = acc[j];
}

// ---------------- fused sequential scan + Y_off (Y +=) ---------------------
__global__ __launch_bounds__(256) void scan_yoff_k(const float* __restrict__ conv,
                                                   const float* __restrict__ dtb,
                                                   const float* __restrict__ acsb,
                                                   float* __restrict__ Y) {
  int pg = blockIdx.x & 3;
  int h = (blockIdx.x >> 2) & 31;
  int b = blockIdx.x >> 7;
  int t = threadIdx.x;
  __shared__ float S[16][260];
  __shared__ float buf[64][68];
  __shared__ float sxs[64][16];
  __shared__ float swt[64];
  __shared__ float sea[64];
  __shared__ float sdec[1];
  for (int i = t; i < 16 * 260; i += 256) ((float*)S)[i] = 0.f;

  int tl = t & 63, tpg = t >> 6;
  int p2 = t >> 4, n2 = (t & 15) * 4;

  for (int c = 0; c < NC; c++) {
    size_t rowbase = ((size_t)(b * SEQL + c * CHUNK)) * CONV_DIMN;
    size_t ab = ((size_t)(b * SEQL + c * CHUNK)) * HEADS;
    {
      int l = t >> 2, i0 = (t & 3) * 4;
      float4 v = *(const float4*)&conv[rowbase + (size_t)l * CONV_DIMN + h * HEAD_DIM + pg * 16 + i0];
      sxs[l][i0 + 0] = v.x; sxs[l][i0 + 1] = v.y;
      sxs[l][i0 + 2] = v.z; sxs[l][i0 + 3] = v.w;
    }
    if (t < 64) {
      float a = acsb[ab + (size_t)t * HEADS + h];
      float alast = acsb[ab + (size_t)63 * HEADS + h];
      swt[t] = expf(alast - a) * dtb[ab + (size_t)t * HEADS + h];
      sea[t] = expf(a);
      if (t == 63) sdec[0] = expf(alast);
    }
    __syncthreads();

    float acc[4] = {0.f, 0.f, 0.f, 0.f};
    for (int nt = 0; nt < 4; nt++) {
      #pragma unroll
      for (int i = 0; i < 16; i++) {
        int e = t + 256 * i;
        int r = e >> 6, col = e & 63;
        buf[r][col] = conv[rowbase + (size_t)r * CONV_DIMN + (D_MODEL + STATE) + nt * 64 + col] * sea[r];
      }
      __syncthreads();
      #pragma unroll 4
      for (int n = 0; n < 64; n += 4) {
        float4 cv = *(const float4*)&buf[tl][n];
        float4 s0 = *(const float4*)&S[tpg * 4 + 0][nt * 64 + n];
        float4 s1 = *(const float4*)&S[tpg * 4 + 1][nt * 64 + n];
        float4 s2 = *(const float4*)&S[tpg * 4 + 2][nt * 64 + n];
        float4 s3 = *(const float4*)&S[tpg * 4 + 3][nt * 64 + n];
        acc[0] += cv.x * s0.x + cv.y * s0.y + cv.z * s0.z + cv.w * s0.w;
        acc[1] += cv.x * s1.x + cv.y * s1.y + cv.z * s1.z + cv.w * s1.w;
        acc[2] += cv.x * s2.x + cv.y * s2.y + cv.z * s2.z + cv.w * s2.w;
        acc[3] += cv.x * s3.x + cv.y * s3.y + cv.z * s3.z + cv.w * s3.w;
      }
      __syncthreads();
    }
    {
      size_t yi = ((size_t)(b * SEQL + c * CHUNK + tl)) * D_MODEL + h * HEAD_DIM + pg * 16 + tpg * 4;
      float4* yp = (float4*)&Y[yi];
      float4 yv = *yp;
      yv.x += acc[0]; yv.y += acc[1]; yv.z += acc[2]; yv.w += acc[3];
      *yp = yv;
    }

    for (int nt = 0; nt < 4; nt++) {
      #pragma unroll
      for (int i = 0; i < 16; i++) {
        int e = t + 256 * i;
        int r = e >> 6, col = e & 63;
        buf[r][col] = conv[rowbase + (size_t)r * CONV_DIMN + D_MODEL + nt * 64 + col] * swt[r];
      }
      __syncthreads();
      float4 ns = {0.f, 0.f, 0.f, 0.f};
      #pragma unroll 4
      for (int l = 0; l < 64; l++) {
        float xw = sxs[l][p2];
        float4 bv = *(const float4*)&buf[l][n2];
        ns.x += bv.x * xw; ns.y += bv.y * xw;
        ns.z += bv.z * xw; ns.w += bv.w * xw;
      }
      float dec = sdec[0];
      float4 sv = *(const float4*)&S[p2][nt * 64 + n2];
      sv.x = sv.x * dec + ns.x; sv.y = sv.y * dec + ns.y;
      sv.z = sv.z * dec + ns.z; sv.w = sv.w * dec + ns.w;
      *(float4*)&S[p2][nt * 64 + n2] = sv;
      __syncthreads();
    }
  }
}

// ---------------- gated RMSNorm -> bf16: yg = rmsnorm(Y * silu(z)) * gw ----
__global__ __launch_bounds__(256) void gated_norm_bf16_k(const float* __restrict__ Y,
                                                         const float* __restrict__ proj,
                                                         const float* __restrict__ gw,
                                                         short* __restrict__ out) {
  int row = blockIdx.x;
  int t = threadIdx.x;
  const float4* y4 = (const float4*)(Y + (size_t)row * D_MODEL);
  const float4* z4 = (const float4*)(proj + (size_t)row * PROJ_DIM);
  float4 ya = y4[2 * t], yb = y4[2 * t + 1];
  float4 za = z4[2 * t], zb = z4[2 * t + 1];
  float4 ga, gb;
  ga.x = ya.x * (za.x / (1.f + expf(-za.x)));
  ga.y = ya.y * (za.y / (1.f + expf(-za.y)));
  ga.z = ya.z * (za.z / (1.f + expf(-za.z)));
  ga.w = ya.w * (za.w / (1.f + expf(-za.w)));
  gb.x = yb.x * (zb.x / (1.f + expf(-zb.x)));
  gb.y = yb.y * (zb.y / (1.f + expf(-zb.y)));
  gb.z = yb.z * (zb.z / (1.f + expf(-zb.z)));
  gb.w = yb.w * (zb.w / (1.f + expf(-zb.w)));
  float ss = ga.x * ga.x + ga.y * ga.y + ga.z * ga.z + ga.w * ga.w +
             gb.x * gb.x + gb.y * gb.y + gb.z * gb.z + gb.w * gb.w;
  #pragma unroll
  for (int off = 32; off > 0; off >>= 1) ss += __shfl_down(ss, off);
  __shared__ float ws_[4];
  if ((t & 63) == 0) ws_[t >> 6] = ss;
  __syncthreads();
  float tot = ws_[0] + ws_[1] + ws_[2] + ws_[3];
  float scale = rsqrtf(tot / (float)D_MODEL + EPSF);
  const float4* g4 = (const float4*)gw;
  float4 wa = g4[2 * t], wb = g4[2 * t + 1];
  short tmp[8];
  tmp[0] = f2bf(ga.x * scale * wa.x); tmp[1] = f2bf(ga.y * scale * wa.y);
  tmp[2] = f2bf(ga.z * scale * wa.z); tmp[3] = f2bf(ga.w * scale * wa.w);
  tmp[4] = f2bf(gb.x * scale * wb.x); tmp[5] = f2bf(gb.y * scale * wb.y);
  tmp[6] = f2bf(gb.z * scale * wb.z); tmp[7] = f2bf(gb.w * scale * wb.w);
  *(int4*)(out + (size_t)row * D_MODEL + t * 8) = *(int4*)tmp;
}

extern "C" void kernel_launch(void* const* d_in, const int* in_sizes, int n_in,
                              void* d_out, int out_size, void* d_ws, size_t ws_size,
                              hipStream_t stream) {
  const float* x       = (const float*)d_in[0];
  const float* norm_w  = (const float*)d_in[1];
  const float* w_in    = (const float*)d_in[2];
  const float* conv_w  = (const float*)d_in[3];
  const float* conv_b  = (const float*)d_in[4];
  const float* dt_bias = (const float*)d_in[5];
  const float* A_log   = (const float*)d_in[6];
  const float* D_skip  = (const float*)d_in[7];
  const float* gnorm_w = (const float*)d_in[8];
  const float* w_out   = (const float*)d_in[9];
  const float* wo_w    = (const float*)d_in[10];
  float* out = (float*)d_out;

  // workspace layout (float units), total 43,384,832 floats = 165.5 MiB
  float* ws     = (float*)d_ws;
  short* xnb    = (short*)ws;                    //  4,194,304 slots (4096x2048 bf16)
  short* w_inT  = (short*)(ws + 4194304);        //  4,849,664 slots (4736x2048 bf16)
  float* proj   = ws + 9043968;                  // 19,005,440
  float* conv   = ws + 28049408;                 // 10,485,760
  float* dtraw  = ws + 38535168;                 //    131,072
  float* dtb    = ws + 38666240;                 //    131,072
  float* acsb   = ws + 38797312;                 //    131,072
  float* CBb    = ws + 38928384;                 //    262,144
  short* w_outT = (short*)(ws + 39190528);       //  2,097,152 slots
  short* wo_wT  = (short*)(ws + 41287680);       //  2,097,152 slots
  float* Yb     = ws;                            // over xnb+w_inT (dead after proj GEMM)
  short* Yg     = (short*)conv;                  // over conv (dead after scan_yoff)
  short* t1b    = (short*)(conv + 4194304);      // over conv tail

  rmsnorm_bf16_k<<<BL, 256, 0, stream>>>(x, norm_w, xnb);
  transpose_bf16_k<<<dim3(NPAD_IN / 32, D_MODEL / 32), 256, 0, stream>>>(w_in, w_inT, D_MODEL, PROJ_DIM, NPAD_IN);
  dt_gemm_k<<<BL, 256, 0, stream>>>(x, norm_w, w_in, dtraw);
  gemm_bt_k<false><<<dim3(NPAD_IN / 128, BL / 128), 256, 0, stream>>>(xnb, w_inT, proj, BL, PROJ_DIM, D_MODEL);
  conv_silu_k<<<(BL * CONV_DIMN) / 256, 256, 0, stream>>>(proj, conv_w, conv_b, conv);
  dt_acs_k<<<BATCHN * NC, 64, 0, stream>>>(dtraw, dt_bias, A_log, dtb, acsb);
  cb_k<<<BATCHN * NC, 256, 0, stream>>>(conv, CBb);
  ydiag_k<<<BATCHN * NC * HEADS, 256, 0, stream>>>(conv, CBb, dtb, acsb, D_skip, Yb);
  scan_yoff_k<<<BATCHN * HEADS * 4, 256, 0, stream>>>(conv, dtb, acsb, Yb);
  gated_norm_bf16_k<<<BL, 256, 0, stream>>>(Yb, proj, gnorm_w, Yg);
  transpose_bf16_k<<<dim3(D_MODEL / 32, D_MODEL / 32), 256, 0, stream>>>(w_out, w_outT, D_MODEL, D_MODEL, D_MODEL);
  transpose_bf16_k<<<dim3(D_MODEL / 32, D_MODEL / 32), 256, 0, stream>>>(wo_w, wo_wT, D_MODEL, D_MODEL, D_MODEL);
  gemm_bt_k<true><<<dim3(D_MODEL / 128, BL / 128), 256, 0, stream>>>(Yg, w_outT, t1b, BL, D_MODEL, D_MODEL);
  gemm_bt_k<false><<<dim3(D_MODEL / 128, BL / 128), 256, 0, stream>>>(t1b, wo_wT, out, BL, D_MODEL, D_MODEL);
}

// Round 4
// 734.277 us; speedup vs baseline: 4.4483x; 2.1040x over previous
//
#include <hip/hip_runtime.h>
#include <math.h>

#define D_MODEL 2048
#define HEADS 32
#define HEAD_DIM 64
#define STATE 256
#define KCONV 4
#define CHUNK 64
#define NC 32            // SEQ / CHUNK
#define SEQL 2048
#define BATCHN 2
#define CONV_DIMN 2560   // D_MODEL + 2*STATE
#define PROJ_DIM 4640    // D_MODEL + CONV_DIM + HEADS
#define NIN 4608         // 36*128: z + xBC cols (dt cols handled by dt_gemm)
#define EPSF 1e-5f
#define BL (BATCHN * SEQL)  // 4096 token rows

typedef __attribute__((ext_vector_type(8))) short short8;
typedef __attribute__((ext_vector_type(4))) short short4v;
typedef __attribute__((ext_vector_type(4))) float f32x4;

__device__ __forceinline__ short f2bf(float f) {
  unsigned u = __builtin_bit_cast(unsigned, f);
  u = (u + 0x7fffu + ((u >> 16) & 1u)) >> 16;   // RNE
  return (short)u;
}
__device__ __forceinline__ float b2f(short s) {
  unsigned u = ((unsigned)(unsigned short)s) << 16;
  return __builtin_bit_cast(float, u);
}
__device__ __forceinline__ void gld16(const void* g, void* l) {
  __builtin_amdgcn_global_load_lds((const __attribute__((address_space(1))) unsigned int*)g,
                                   (__attribute__((address_space(3))) unsigned int*)l,
                                   16, 0, 0);
}

// ---------------- RMSNorm -> bf16 ------------------------------------------
__global__ __launch_bounds__(256) void rmsnorm_bf16_k(const float* __restrict__ x,
                                                      const float* __restrict__ w,
                                                      short* __restrict__ out) {
  int row = blockIdx.x;
  int t = threadIdx.x;
  const float4* x4 = (const float4*)(x + (size_t)row * D_MODEL);
  float4 va = x4[2 * t], vb = x4[2 * t + 1];
  float ss = va.x * va.x + va.y * va.y + va.z * va.z + va.w * va.w +
             vb.x * vb.x + vb.y * vb.y + vb.z * vb.z + vb.w * vb.w;
  #pragma unroll
  for (int off = 32; off > 0; off >>= 1) ss += __shfl_down(ss, off);
  __shared__ float ws_[4];
  if ((t & 63) == 0) ws_[t >> 6] = ss;
  __syncthreads();
  float tot = ws_[0] + ws_[1] + ws_[2] + ws_[3];
  float scale = rsqrtf(tot / (float)D_MODEL + EPSF);
  const float4* w4 = (const float4*)w;
  float4 wa = w4[2 * t], wb = w4[2 * t + 1];
  short tmp[8];
  tmp[0] = f2bf(va.x * scale * wa.x); tmp[1] = f2bf(va.y * scale * wa.y);
  tmp[2] = f2bf(va.z * scale * wa.z); tmp[3] = f2bf(va.w * scale * wa.w);
  tmp[4] = f2bf(vb.x * scale * wb.x); tmp[5] = f2bf(vb.y * scale * wb.y);
  tmp[6] = f2bf(vb.z * scale * wb.z); tmp[7] = f2bf(vb.w * scale * wb.w);
  *(int4*)(out + (size_t)row * D_MODEL + t * 8) = *(int4*)tmp;
}

// ---------------- transpose + fp32->bf16: W[K,N] -> WT[n<gridN][K] ---------
__global__ __launch_bounds__(256) void transpose_bf16_k(const float* __restrict__ W,
                                                        short* __restrict__ WT,
                                                        int K, int N) {
  __shared__ float tile[32][33];
  int bn = blockIdx.x * 32, bk = blockIdx.y * 32;
  int tx = threadIdx.x & 31, ty = threadIdx.x >> 5;  // ty 0..7
  #pragma unroll
  for (int i = 0; i < 32; i += 8) {
    int k = bk + ty + i, n = bn + tx;
    tile[ty + i][tx] = (n < N) ? W[(size_t)k * N + n] : 0.f;
  }
  __syncthreads();
  #pragma unroll
  for (int i = 0; i < 32; i += 8) {
    int n = bn + ty + i, k = bk + tx;
    WT[(size_t)n * K + k] = f2bf(tile[tx][ty + i]);
  }
}

// ---------------- fp32 dt head-projection ----------------------------------
__global__ __launch_bounds__(256) void dt_gemm_k(const float* __restrict__ x,
                                                 const float* __restrict__ norm_w,
                                                 const float* __restrict__ w_in,
                                                 float* __restrict__ dtraw) {
  int row = blockIdx.x;
  int t = threadIdx.x;
  __shared__ float sx[D_MODEL];
  __shared__ float red[8][32];
  __shared__ float sred[4];
  const float4* x4 = (const float4*)(x + (size_t)row * D_MODEL);
  const float4* nw4 = (const float4*)norm_w;
  float ss = 0.f;
  for (int i = t; i < D_MODEL / 4; i += 256) {
    float4 v = x4[i];
    ss += v.x * v.x + v.y * v.y + v.z * v.z + v.w * v.w;
    float4 nw = nw4[i];
    float4 pv; pv.x = v.x * nw.x; pv.y = v.y * nw.y; pv.z = v.z * nw.z; pv.w = v.w * nw.w;
    ((float4*)sx)[i] = pv;
  }
  #pragma unroll
  for (int off = 32; off > 0; off >>= 1) ss += __shfl_down(ss, off);
  if ((t & 63) == 0) sred[t >> 6] = ss;
  __syncthreads();
  float tot = sred[0] + sred[1] + sred[2] + sred[3];
  float scale = rsqrtf(tot / (float)D_MODEL + EPSF);
  int h = t & 31, sl = t >> 5;
  float acc = 0.f;
  for (int k = sl * 256; k < sl * 256 + 256; k++)
    acc += sx[k] * w_in[(size_t)k * PROJ_DIM + (D_MODEL + CONV_DIMN) + h];
  red[sl][h] = acc;
  __syncthreads();
  if (t < 32) {
    float s = 0.f;
    #pragma unroll
    for (int i = 0; i < 8; i++) s += red[i][t];
    dtraw[(size_t)row * HEADS + t] = s * scale;
  }
}

// ---------------- bf16 MFMA GEMM (generic, out fp32 or bf16) ---------------
template<bool BF16OUT>
__global__ __launch_bounds__(256) void gemm_bt_k(const short* __restrict__ A,
                                                 const short* __restrict__ BT,
                                                 void* __restrict__ Cout,
                                                 int M, int N, int K) {
  __shared__ short sA[4096];
  __shared__ short sB[4096];
  int t = threadIdx.x;
  int lane = t & 63, w = t >> 6;
  int m0 = blockIdx.y * 128, n0 = blockIdx.x * 128;
  f32x4 acc[4][4] = {};
  int rS[2], ksS[2];
  #pragma unroll
  for (int ld = 0; ld < 2; ld++) {
    int c = w + ld * 4;
    int r = c * 16 + (lane >> 2);
    rS[ld] = r;
    ksS[ld] = (((lane & 3) ^ ((r >> 1) & 3))) * 8;
  }
  int q = lane >> 4, mr = lane & 15;
  int wm = (w & 1) * 64, wn = (w >> 1) * 64;
  int aoff[4], boff[4];
  #pragma unroll
  for (int i = 0; i < 4; i++) {
    int r = wm + i * 16 + mr;
    aoff[i] = r * 32 + (q ^ ((r >> 1) & 3)) * 8;
    int rn = wn + i * 16 + mr;
    boff[i] = rn * 32 + (q ^ ((rn >> 1) & 3)) * 8;
  }
  for (int k0 = 0; k0 < K; k0 += 32) {
    __syncthreads();
    #pragma unroll
    for (int ld = 0; ld < 2; ld++) {
      int c = w + ld * 4;
      gld16(A + (size_t)(m0 + rS[ld]) * K + k0 + ksS[ld], &sA[c * 512]);
      gld16(BT + (size_t)(n0 + rS[ld]) * K + k0 + ksS[ld], &sB[c * 512]);
    }
    __syncthreads();
    short8 af[4], bfr[4];
    #pragma unroll
    for (int i = 0; i < 4; i++) af[i] = *(const short8*)&sA[aoff[i]];
    #pragma unroll
    for (int i = 0; i < 4; i++) bfr[i] = *(const short8*)&sB[boff[i]];
    #pragma unroll
    for (int mi = 0; mi < 4; mi++)
      #pragma unroll
      for (int ni = 0; ni < 4; ni++)
        acc[mi][ni] = __builtin_amdgcn_mfma_f32_16x16x32_bf16(af[mi], bfr[ni], acc[mi][ni], 0, 0, 0);
  }
  int orow = (lane >> 4) * 4, ocol = lane & 15;
  #pragma unroll
  for (int mi = 0; mi < 4; mi++) {
    #pragma unroll
    for (int ni = 0; ni < 4; ni++) {
      int gn = n0 + wn + ni * 16 + ocol;
      if (gn >= N) continue;
      #pragma unroll
      for (int r = 0; r < 4; r++) {
        int gm = m0 + wm + mi * 16 + orow + r;
        if (BF16OUT) ((short*)Cout)[(size_t)gm * N + gn] = f2bf(acc[mi][ni][r]);
        else         ((float*)Cout)[(size_t)gm * N + gn] = acc[mi][ni][r];
      }
    }
  }
}

// ---------------- proj GEMM with split epilogue: z->bf16, xBC->fp32 --------
__global__ __launch_bounds__(256) void gemm_in_k(const short* __restrict__ A,
                                                 const short* __restrict__ BT,
                                                 short* __restrict__ zb,
                                                 float* __restrict__ xbc,
                                                 int M, int K) {
  __shared__ short sA[4096];
  __shared__ short sB[4096];
  int t = threadIdx.x;
  int lane = t & 63, w = t >> 6;
  int m0 = blockIdx.y * 128, n0 = blockIdx.x * 128;
  f32x4 acc[4][4] = {};
  int rS[2], ksS[2];
  #pragma unroll
  for (int ld = 0; ld < 2; ld++) {
    int c = w + ld * 4;
    int r = c * 16 + (lane >> 2);
    rS[ld] = r;
    ksS[ld] = (((lane & 3) ^ ((r >> 1) & 3))) * 8;
  }
  int q = lane >> 4, mr = lane & 15;
  int wm = (w & 1) * 64, wn = (w >> 1) * 64;
  int aoff[4], boff[4];
  #pragma unroll
  for (int i = 0; i < 4; i++) {
    int r = wm + i * 16 + mr;
    aoff[i] = r * 32 + (q ^ ((r >> 1) & 3)) * 8;
    int rn = wn + i * 16 + mr;
    boff[i] = rn * 32 + (q ^ ((rn >> 1) & 3)) * 8;
  }
  for (int k0 = 0; k0 < K; k0 += 32) {
    __syncthreads();
    #pragma unroll
    for (int ld = 0; ld < 2; ld++) {
      int c = w + ld * 4;
      gld16(A + (size_t)(m0 + rS[ld]) * K + k0 + ksS[ld], &sA[c * 512]);
      gld16(BT + (size_t)(n0 + rS[ld]) * K + k0 + ksS[ld], &sB[c * 512]);
    }
    __syncthreads();
    short8 af[4], bfr[4];
    #pragma unroll
    for (int i = 0; i < 4; i++) af[i] = *(const short8*)&sA[aoff[i]];
    #pragma unroll
    for (int i = 0; i < 4; i++) bfr[i] = *(const short8*)&sB[boff[i]];
    #pragma unroll
    for (int mi = 0; mi < 4; mi++)
      #pragma unroll
      for (int ni = 0; ni < 4; ni++)
        acc[mi][ni] = __builtin_amdgcn_mfma_f32_16x16x32_bf16(af[mi], bfr[ni], acc[mi][ni], 0, 0, 0);
  }
  int orow = (lane >> 4) * 4, ocol = lane & 15;
  #pragma unroll
  for (int mi = 0; mi < 4; mi++) {
    #pragma unroll
    for (int ni = 0; ni < 4; ni++) {
      int gn = n0 + wn + ni * 16 + ocol;
      #pragma unroll
      for (int r = 0; r < 4; r++) {
        int gm = m0 + wm + mi * 16 + orow + r;
        float v = acc[mi][ni][r];
        if (gn < D_MODEL) zb[(size_t)gm * D_MODEL + gn] = f2bf(v);
        else              xbc[(size_t)gm * CONV_DIMN + (gn - D_MODEL)] = v;
      }
    }
  }
}

// ---------------- depthwise causal conv + bias + SiLU -> bf16 --------------
__global__ __launch_bounds__(256) void conv_silu_k(const float* __restrict__ xbc,
                                                   const float* __restrict__ cw,
                                                   const float* __restrict__ cb,
                                                   short* __restrict__ out) {
  int idx = blockIdx.x * 256 + threadIdx.x;   // BL * CONV_DIM total
  int c = idx % CONV_DIMN;
  int bt = idx / CONV_DIMN;
  int t = bt % SEQL;
  int b = bt / SEQL;
  float acc = cb[c];
  #pragma unroll
  for (int k = 0; k < KCONV; k++) {
    int tt = t - (KCONV - 1) + k;
    if (tt >= 0)
      acc += xbc[((size_t)(b * SEQL + tt)) * CONV_DIMN + c] * cw[c * KCONV + k];
  }
  out[idx] = f2bf(acc / (1.f + expf(-acc)));
}

// ---------------- dt softplus + per-chunk cumsum of A*dt -------------------
__global__ void dt_acs_k(const float* __restrict__ dtraw,
                         const float* __restrict__ dt_bias,
                         const float* __restrict__ A_log,
                         float* __restrict__ dtb, float* __restrict__ acsb) {
  int bc = blockIdx.x;
  int b = bc / NC, c = bc % NC;
  int l = threadIdx.x;  // 0..63
  int tok = c * CHUNK + l;
  size_t base = ((size_t)(b * SEQL + tok)) * HEADS;
  for (int h = 0; h < HEADS; h++) {
    float raw = dtraw[base + h] + dt_bias[h];
    float dt = raw > 20.f ? raw : log1pf(expf(raw));
    float adt = -expf(A_log[h]) * dt;
    float cs = adt;
    #pragma unroll
    for (int off = 1; off < 64; off <<= 1) {
      float v = __shfl_up(cs, off);
      if (l >= off) cs += v;
    }
    dtb[base + h] = dt;
    acsb[base + h] = cs;
  }
}

// ---------------- CB[b,c,l,s] = sum_n C(l,n) * B(s,n) ----------------------
__global__ __launch_bounds__(256) void cb_k(const short* __restrict__ convb,
                                            float* __restrict__ CB) {
  int bc = blockIdx.x;
  int b = bc / NC, c = bc % NC;
  __shared__ float sC[64][65];
  __shared__ float sB[64][65];
  int t = threadIdx.x;
  int s = t & 63;
  int lb = (t >> 6) * 16;
  float acc[16] = {};
  size_t rowb = ((size_t)(b * SEQL + c * CHUNK)) * CONV_DIMN;
  for (int nt = 0; nt < 4; nt++) {
    __syncthreads();
    #pragma unroll
    for (int i = 0; i < 16; i++) {
      int e = t + 256 * i;
      int r = e >> 6, col = e & 63;
      sC[r][col] = b2f(convb[rowb + (size_t)r * CONV_DIMN + (D_MODEL + STATE) + nt * 64 + col]);
      sB[r][col] = b2f(convb[rowb + (size_t)r * CONV_DIMN + D_MODEL + nt * 64 + col]);
    }
    __syncthreads();
    for (int n = 0; n < 64; n++) {
      float bv = sB[s][n];
      #pragma unroll
      for (int j = 0; j < 16; j++) acc[j] += sC[lb + j][n] * bv;
    }
  }
  size_t ob = ((size_t)bc) * 64 * 64;
  #pragma unroll
  for (int j = 0; j < 16; j++) CB[ob + (size_t)(lb + j) * 64 + s] = acc[j];
}

// ---------------- chunk states via MFMA: G[p][n] = sum_l xsw(p,l)*B(l,n) ---
__global__ __launch_bounds__(256) void chunk_states_k(const short* __restrict__ convb,
                                                      const float* __restrict__ dtb,
                                                      const float* __restrict__ acsb,
                                                      short* __restrict__ G) {
  int blk = blockIdx.x;            // ((b*NC)+c)*HEADS + h
  int h = blk & 31, c = (blk >> 5) & 31, b = blk >> 10;
  __shared__ short sXT[64][72];    // [p][l] = bf16(xs(l,p) * wt(l)), 16B rows
  __shared__ short sBT[256][72];   // [n][l] = B(l,n)
  __shared__ float swt[64];
  int t = threadIdx.x;
  size_t rowb = ((size_t)(b * SEQL + c * CHUNK)) * CONV_DIMN;
  size_t ab = ((size_t)(b * SEQL + c * CHUNK)) * HEADS;
  if (t < 64) {
    float a = acsb[ab + (size_t)t * HEADS + h];
    float alast = acsb[ab + (size_t)63 * HEADS + h];
    swt[t] = expf(alast - a) * dtb[ab + (size_t)t * HEADS + h];
  }
  __syncthreads();
  // stage xs^T * wt : 64l x 64p
  #pragma unroll
  for (int i = 0; i < 4; i++) {
    int e = t + 256 * i;                 // 1024 quads
    int l = e >> 4, p4 = (e & 15) * 4;
    short4v v = *(const short4v*)&convb[rowb + (size_t)l * CONV_DIMN + h * HEAD_DIM + p4];
    float wt = swt[l];
    sXT[p4 + 0][l] = f2bf(b2f(v.x) * wt);
    sXT[p4 + 1][l] = f2bf(b2f(v.y) * wt);
    sXT[p4 + 2][l] = f2bf(b2f(v.z) * wt);
    sXT[p4 + 3][l] = f2bf(b2f(v.w) * wt);
  }
  // stage B^T : 64l x 256n
  #pragma unroll
  for (int i = 0; i < 16; i++) {
    int e = t + 256 * i;                 // 4096 quads
    int l = e >> 6, n4 = (e & 63) * 4;
    short4v v = *(const short4v*)&convb[rowb + (size_t)l * CONV_DIMN + D_MODEL + n4];
    sBT[n4 + 0][l] = v.x;
    sBT[n4 + 1][l] = v.y;
    sBT[n4 + 2][l] = v.z;
    sBT[n4 + 3][l] = v.w;
  }
  __syncthreads();
  int lane = t & 63, w = t >> 6;
  int mr = lane & 15, q = lane >> 4;
  f32x4 acc[4][4] = {};
  #pragma unroll
  for (int ks = 0; ks < 2; ks++) {
    short8 af[4], bfr[4];
    #pragma unroll
    for (int mi = 0; mi < 4; mi++) af[mi] = *(const short8*)&sXT[mi * 16 + mr][ks * 32 + q * 8];
    #pragma unroll
    for (int ni = 0; ni < 4; ni++) bfr[ni] = *(const short8*)&sBT[w * 64 + ni * 16 + mr][ks * 32 + q * 8];
    #pragma unroll
    for (int mi = 0; mi < 4; mi++)
      #pragma unroll
      for (int ni = 0; ni < 4; ni++)
        acc[mi][ni] = __builtin_amdgcn_mfma_f32_16x16x32_bf16(af[mi], bfr[ni], acc[mi][ni], 0, 0, 0);
  }
  size_t gb = (size_t)blk * (64 * 256);
  #pragma unroll
  for (int mi = 0; mi < 4; mi++)
    #pragma unroll
    for (int ni = 0; ni < 4; ni++)
      #pragma unroll
      for (int r = 0; r < 4; r++)
        G[gb + (size_t)(mi * 16 + q * 4 + r) * 256 + w * 64 + ni * 16 + mr] = f2bf(acc[mi][ni][r]);
}

// ---------------- sequential chunk recursion, in-place exclusive prefix ----
__global__ __launch_bounds__(256) void scan_states_k(short* __restrict__ G,
                                                     const float* __restrict__ acsb) {
  int gid = blockIdx.x * 256 + threadIdx.x;   // 2^19 threads
  int np = gid & 127;
  int p  = (gid >> 7) & 63;
  int h  = (gid >> 13) & 31;
  int b  = gid >> 18;
  float S0 = 0.f, S1 = 0.f;
  for (int c = 0; c < NC; c++) {
    size_t base = ((((size_t)((b * NC + c) * HEADS + h)) * 64) + p) * 256 + np * 2;
    unsigned u = *(const unsigned*)&G[base];
    float g0 = b2f((short)(u & 0xffff));
    float g1 = b2f((short)(u >> 16));
    unsigned wv = (unsigned)(unsigned short)f2bf(S0) | ((unsigned)(unsigned short)f2bf(S1) << 16);
    *(unsigned*)&G[base] = wv;
    float dec = expf(acsb[((size_t)(b * SEQL + c * CHUNK + 63)) * HEADS + h]);
    S0 = S0 * dec + g0;
    S1 = S1 * dec + g1;
  }
}

// ---------------- Y_diag + D*xs (writes Y) ---------------------------------
__global__ __launch_bounds__(256) void ydiag_k(const short* __restrict__ convb,
                                               const float* __restrict__ CB,
                                               const float* __restrict__ dtb,
                                               const float* __restrict__ acsb,
                                               const float* __restrict__ D_skip,
                                               float* __restrict__ Y) {
  int blk = blockIdx.x;            // ((b*NC)+c)*HEADS + h
  int h = blk & 31, c = (blk >> 5) & 31, b = blk >> 10;
  __shared__ float buf1[64][65];   // xs(l,p)
  __shared__ float buf2[64][65];   // CB -> M(l,s)
  __shared__ float sdt[64], sacs[64];
  int t = threadIdx.x;
  int p = t & 63;
  int lb = (t >> 6) * 16;
  size_t rowb = ((size_t)(b * SEQL + c * CHUNK)) * CONV_DIMN;
  size_t ab = ((size_t)(b * SEQL + c * CHUNK)) * HEADS;
  size_t cbbase = ((size_t)(b * NC + c)) * 64 * 64;
  #pragma unroll
  for (int i = 0; i < 16; i++) {
    int e = t + 256 * i;
    int r = e >> 6, col = e & 63;
    buf1[r][col] = b2f(convb[rowb + (size_t)r * CONV_DIMN + h * HEAD_DIM + col]);
    buf2[r][col] = CB[cbbase + (size_t)r * 64 + col];
  }
  if (t < 64) {
    sacs[t] = acsb[ab + (size_t)t * HEADS + h];
    sdt[t] = dtb[ab + (size_t)t * HEADS + h];
  }
  __syncthreads();
  #pragma unroll
  for (int i = 0; i < 16; i++) {
    int e = t + 256 * i;
    int r = e >> 6, col = e & 63;  // r=l, col=s
    float m = 0.f;
    if (col <= r) m = buf2[r][col] * expf(sacs[r] - sacs[col]) * sdt[col];
    buf2[r][col] = m;
  }
  __syncthreads();
  float acc[16];
  float dsk = D_skip[h];
  #pragma unroll
  for (int j = 0; j < 16; j++) acc[j] = dsk * buf1[lb + j][p];
  for (int s = 0; s < 64; s++) {
    float xv = buf1[s][p];
    #pragma unroll
    for (int j = 0; j < 16; j++) acc[j] += buf2[lb + j][s] * xv;
  }
  size_t ybase = ((size_t)(b * SEQL + c * CHUNK)) * D_MODEL + h * HEAD_DIM;
  #pragma unroll
  for (int j = 0; j < 16; j++) Y[ybase + (size_t)(lb + j) * D_MODEL + p] = acc[j];
}

// ---------------- Y_off via MFMA: Y(l,p) += sum_n Ce(l,n)*prevS(p,n) -------
__global__ __launch_bounds__(256) void yoff_k(const short* __restrict__ convb,
                                              const short* __restrict__ G,
                                              const float* __restrict__ acsb,
                                              float* __restrict__ Y) {
  int blk = blockIdx.x;            // ((b*NC)+c)*HEADS + h
  int h = blk & 31, c = (blk >> 5) & 31, b = blk >> 10;
  __shared__ short sCe[64][264];   // [l][n] = bf16(C(l,n) * exp(acs_l))
  __shared__ short sS[64 * 256];   // [p][n], 16B-chunk XOR-swizzled by (p&7)
  __shared__ float sea[64];
  int t = threadIdx.x;
  int lane = t & 63, w = t >> 6;
  size_t rowb = ((size_t)(b * SEQL + c * CHUNK)) * CONV_DIMN;
  size_t ab = ((size_t)(b * SEQL + c * CHUNK)) * HEADS;
  if (t < 64) sea[t] = expf(acsb[ab + (size_t)t * HEADS + h]);
  __syncthreads();
  // stage prevS rows via global_load_lds (2 rows per instr per wave)
  size_t gbase = (size_t)blk * (64 * 256);
  int j = lane & 31;
  #pragma unroll
  for (int it = 0; it < 8; it++) {
    int r = w * 16 + it * 2 + (lane >> 5);
    int srcchunk = j ^ (r & 7);
    gld16(G + gbase + (size_t)r * 256 + srcchunk * 8, &sS[(w * 16 + it * 2) * 256]);
  }
  // stage Ce (VALU)
  #pragma unroll
  for (int i = 0; i < 32; i++) {
    int e = t + 256 * i;             // 8192 short2-pairs
    int l = e >> 7, n2 = (e & 127) * 2;
    unsigned u = *(const unsigned*)&convb[rowb + (size_t)l * CONV_DIMN + (D_MODEL + STATE) + n2];
    float el = sea[l];
    sCe[l][n2 + 0] = f2bf(b2f((short)(u & 0xffff)) * el);
    sCe[l][n2 + 1] = f2bf(b2f((short)(u >> 16)) * el);
  }
  __syncthreads();
  int mr = lane & 15, q = lane >> 4;
  int wm = (w & 1) * 32, wn = (w >> 1) * 32;
  f32x4 acc[2][2] = {};
  #pragma unroll
  for (int st = 0; st < 8; st++) {
    short8 af[2], bfr[2];
    #pragma unroll
    for (int mi = 0; mi < 2; mi++)
      af[mi] = *(const short8*)&sCe[wm + mi * 16 + mr][st * 32 + q * 8];
    #pragma unroll
    for (int ni = 0; ni < 2; ni++) {
      int p = wn + ni * 16 + mr;
      int cc = st * 4 + q;
      bfr[ni] = *(const short8*)&sS[p * 256 + ((cc ^ (p & 7)) * 8)];
    }
    #pragma unroll
    for (int mi = 0; mi < 2; mi++)
      #pragma unroll
      for (int ni = 0; ni < 2; ni++)
        acc[mi][ni] = __builtin_amdgcn_mfma_f32_16x16x32_bf16(af[mi], bfr[ni], acc[mi][ni], 0, 0, 0);
  }
  size_t ybase = ((size_t)(b * SEQL + c * CHUNK)) * D_MODEL + h * HEAD_DIM;
  #pragma unroll
  for (int mi = 0; mi < 2; mi++)
    #pragma unroll
    for (int ni = 0; ni < 2; ni++)
      #pragma unroll
      for (int r = 0; r < 4; r++) {
        int l = wm + mi * 16 + q * 4 + r;
        int p = wn + ni * 16 + mr;
        Y[ybase + (size_t)l * D_MODEL + p] += acc[mi][ni][r];
      }
}

// ---------------- gated RMSNorm -> bf16 (z from bf16 buffer) ---------------
__global__ __launch_bounds__(256) void gated_norm_bf16_k(const float* __restrict__ Y,
                                                         const short* __restrict__ zb,
                                                         const float* __restrict__ gw,
                                                         short* __restrict__ out) {
  int row = blockIdx.x;
  int t = threadIdx.x;
  const float4* y4 = (const float4*)(Y + (size_t)row * D_MODEL);
  float4 ya = y4[2 * t], yb = y4[2 * t + 1];
  short zt[8];
  *(int4*)zt = *(const int4*)(zb + (size_t)row * D_MODEL + t * 8);
  float g[8];
  float yv[8] = {ya.x, ya.y, ya.z, ya.w, yb.x, yb.y, yb.z, yb.w};
  float ss = 0.f;
  #pragma unroll
  for (int i = 0; i < 8; i++) {
    float z = b2f(zt[i]);
    g[i] = yv[i] * (z / (1.f + expf(-z)));
    ss += g[i] * g[i];
  }
  #pragma unroll
  for (int off = 32; off > 0; off >>= 1) ss += __shfl_down(ss, off);
  __shared__ float ws_[4];
  if ((t & 63) == 0) ws_[t >> 6] = ss;
  __syncthreads();
  float tot = ws_[0] + ws_[1] + ws_[2] + ws_[3];
  float scale = rsqrtf(tot / (float)D_MODEL + EPSF);
  const float4* g4 = (const float4*)gw;
  float4 wa = g4[2 * t], wb = g4[2 * t + 1];
  float wv[8] = {wa.x, wa.y, wa.z, wa.w, wb.x, wb.y, wb.z, wb.w};
  short tmp[8];
  #pragma unroll
  for (int i = 0; i < 8; i++) tmp[i] = f2bf(g[i] * scale * wv[i]);
  *(int4*)(out + (size_t)row * D_MODEL + t * 8) = *(int4*)tmp;
}

extern "C" void kernel_launch(void* const* d_in, const int* in_sizes, int n_in,
                              void* d_out, int out_size, void* d_ws, size_t ws_size,
                              hipStream_t stream) {
  const float* x       = (const float*)d_in[0];
  const float* norm_w  = (const float*)d_in[1];
  const float* w_in    = (const float*)d_in[2];
  const float* conv_w  = (const float*)d_in[3];
  const float* conv_b  = (const float*)d_in[4];
  const float* dt_bias = (const float*)d_in[5];
  const float* A_log   = (const float*)d_in[6];
  const float* D_skip  = (const float*)d_in[7];
  const float* gnorm_w = (const float*)d_in[8];
  const float* w_out   = (const float*)d_in[9];
  const float* wo_w    = (const float*)d_in[10];
  float* out = (float*)d_out;

  // workspace (float units), total 42,074,112 fu = 160.5 MiB
  float* ws    = (float*)d_ws;
  short* xnb   = (short*)ws;                 // [0 .. 4,194,304)      bf16 4096x2048
  short* w_inT = (short*)(ws + 4194304);     // 4,718,592 fu          bf16 4608x2048
  float* xbc   = ws + 8912896;               // 10,485,760 fu         fp32 4096x2560
  short* zb    = (short*)(ws + 19398656);    // 4,194,304 fu          bf16 4096x2048
  short* convb = (short*)(ws + 23592960);    // 5,242,880 fu          bf16 4096x2560
  float* dtraw = ws + 28835840;              // 131,072
  float* dtb   = ws + 28966912;              // 131,072
  float* acsb  = ws + 29097984;              // 131,072
  float* CBb   = ws + 29229056;              // 262,144
  float* Yb    = ws + 29491200;              // 8,388,608
  short* w_outT= (short*)(ws + 37879808);    // 2,097,152 fu
  short* wo_wT = (short*)(ws + 39976960);    // 2,097,152 fu
  short* G     = (short*)ws;                 // overlays [0..16,777,216 fu); live steps 9-12
  short* Yg    = convb;                      // overlays convb after yoff
  short* t1b   = (short*)ws;                 // overlays G region after yoff

  rmsnorm_bf16_k<<<BL, 256, 0, stream>>>(x, norm_w, xnb);
  transpose_bf16_k<<<dim3(NIN / 32, D_MODEL / 32), 256, 0, stream>>>(w_in, w_inT, D_MODEL, PROJ_DIM);
  transpose_bf16_k<<<dim3(D_MODEL / 32, D_MODEL / 32), 256, 0, stream>>>(w_out, w_outT, D_MODEL, D_MODEL);
  transpose_bf16_k<<<dim3(D_MODEL / 32, D_MODEL / 32), 256, 0, stream>>>(wo_w, wo_wT, D_MODEL, D_MODEL);
  dt_gemm_k<<<BL, 256, 0, stream>>>(x, norm_w, w_in, dtraw);
  gemm_in_k<<<dim3(NIN / 128, BL / 128), 256, 0, stream>>>(xnb, w_inT, zb, xbc, BL, D_MODEL);
  conv_silu_k<<<(BL * CONV_DIMN) / 256, 256, 0, stream>>>(xbc, conv_w, conv_b, convb);
  dt_acs_k<<<BATCHN * NC, 64, 0, stream>>>(dtraw, dt_bias, A_log, dtb, acsb);
  cb_k<<<BATCHN * NC, 256, 0, stream>>>(convb, CBb);
  chunk_states_k<<<BATCHN * NC * HEADS, 256, 0, stream>>>(convb, dtb, acsb, G);
  scan_states_k<<<2048, 256, 0, stream>>>(G, acsb);
  ydiag_k<<<BATCHN * NC * HEADS, 256, 0, stream>>>(convb, CBb, dtb, acsb, D_skip, Yb);
  yoff_k<<<BATCHN * NC * HEADS, 256, 0, stream>>>(convb, G, acsb, Yb);
  gated_norm_bf16_k<<<BL, 256, 0, stream>>>(Yb, zb, gnorm_w, Yg);
  gemm_bt_k<true><<<dim3(D_MODEL / 128, BL / 128), 256, 0, stream>>>(Yg, w_outT, t1b, BL, D_MODEL, D_MODEL);
  gemm_bt_k<false><<<dim3(D_MODEL / 128, BL / 128), 256, 0, stream>>>(t1b, wo_wT, out, BL, D_MODEL, D_MODEL);
}

// Round 5
// 696.178 us; speedup vs baseline: 4.6918x; 1.0547x over previous
//
#include <hip/hip_runtime.h>
#include <math.h>

#define D_MODEL 2048
#define HEADS 32
#define HEAD_DIM 64
#define STATE 256
#define KCONV 4
#define CHUNK 64
#define NC 32            // SEQ / CHUNK
#define SEQL 2048
#define BATCHN 2
#define CONV_DIMN 2560   // D_MODEL + 2*STATE
#define PROJ_DIM 4640    // D_MODEL + CONV_DIM + HEADS
#define PROJB_W 4608     // 36*128: z + xBC cols (dt handled by dt_gemm)
#define EPSF 1e-5f
#define BL (BATCHN * SEQL)  // 4096 token rows

typedef __attribute__((ext_vector_type(8))) short short8;
typedef __attribute__((ext_vector_type(4))) short short4v;
typedef __attribute__((ext_vector_type(4))) float f32x4;

__device__ __forceinline__ short f2bf(float f) {
  unsigned u = __builtin_bit_cast(unsigned, f);
  u = (u + 0x7fffu + ((u >> 16) & 1u)) >> 16;   // RNE
  return (short)u;
}
__device__ __forceinline__ float b2f(short s) {
  unsigned u = ((unsigned)(unsigned short)s) << 16;
  return __builtin_bit_cast(float, u);
}
__device__ __forceinline__ void gld16(const void* g, void* l) {
  __builtin_amdgcn_global_load_lds((const __attribute__((address_space(1))) unsigned int*)g,
                                   (__attribute__((address_space(3))) unsigned int*)l,
                                   16, 0, 0);
}

// ---------------- RMSNorm -> bf16 ------------------------------------------
__global__ __launch_bounds__(256) void rmsnorm_bf16_k(const float* __restrict__ x,
                                                      const float* __restrict__ w,
                                                      short* __restrict__ out) {
  int row = blockIdx.x;
  int t = threadIdx.x;
  const float4* x4 = (const float4*)(x + (size_t)row * D_MODEL);
  float4 va = x4[2 * t], vb = x4[2 * t + 1];
  float ss = va.x * va.x + va.y * va.y + va.z * va.z + va.w * va.w +
             vb.x * vb.x + vb.y * vb.y + vb.z * vb.z + vb.w * vb.w;
  #pragma unroll
  for (int off = 32; off > 0; off >>= 1) ss += __shfl_down(ss, off);
  __shared__ float ws_[4];
  if ((t & 63) == 0) ws_[t >> 6] = ss;
  __syncthreads();
  float tot = ws_[0] + ws_[1] + ws_[2] + ws_[3];
  float scale = rsqrtf(tot / (float)D_MODEL + EPSF);
  const float4* w4 = (const float4*)w;
  float4 wa = w4[2 * t], wb = w4[2 * t + 1];
  short tmp[8];
  tmp[0] = f2bf(va.x * scale * wa.x); tmp[1] = f2bf(va.y * scale * wa.y);
  tmp[2] = f2bf(va.z * scale * wa.z); tmp[3] = f2bf(va.w * scale * wa.w);
  tmp[4] = f2bf(vb.x * scale * wb.x); tmp[5] = f2bf(vb.y * scale * wb.y);
  tmp[6] = f2bf(vb.z * scale * wb.z); tmp[7] = f2bf(vb.w * scale * wb.w);
  *(int4*)(out + (size_t)row * D_MODEL + t * 8) = *(int4*)tmp;
}

// ---------------- transpose + fp32->bf16 -----------------------------------
__global__ __launch_bounds__(256) void transpose_bf16_k(const float* __restrict__ W,
                                                        short* __restrict__ WT,
                                                        int K, int ncols, int stride) {
  __shared__ float tile[32][33];
  int bn = blockIdx.x * 32, bk = blockIdx.y * 32;
  int tx = threadIdx.x & 31, ty = threadIdx.x >> 5;  // ty 0..7
  #pragma unroll
  for (int i = 0; i < 32; i += 8) {
    int k = bk + ty + i, n = bn + tx;
    tile[ty + i][tx] = (n < ncols) ? W[(size_t)k * stride + n] : 0.f;
  }
  __syncthreads();
  #pragma unroll
  for (int i = 0; i < 32; i += 8) {
    int n = bn + ty + i, k = bk + tx;
    WT[(size_t)n * K + k] = f2bf(tile[tx][ty + i]);
  }
}

// ---------------- fp32 dt head-projection ----------------------------------
__global__ __launch_bounds__(256) void dt_gemm_k(const float* __restrict__ x,
                                                 const float* __restrict__ norm_w,
                                                 const float* __restrict__ w_in,
                                                 float* __restrict__ dtraw) {
  int row = blockIdx.x;
  int t = threadIdx.x;
  __shared__ float sx[D_MODEL];
  __shared__ float red[8][32];
  __shared__ float sred[4];
  const float4* x4 = (const float4*)(x + (size_t)row * D_MODEL);
  const float4* nw4 = (const float4*)norm_w;
  float ss = 0.f;
  for (int i = t; i < D_MODEL / 4; i += 256) {
    float4 v = x4[i];
    ss += v.x * v.x + v.y * v.y + v.z * v.z + v.w * v.w;
    float4 nw = nw4[i];
    float4 pv; pv.x = v.x * nw.x; pv.y = v.y * nw.y; pv.z = v.z * nw.z; pv.w = v.w * nw.w;
    ((float4*)sx)[i] = pv;
  }
  #pragma unroll
  for (int off = 32; off > 0; off >>= 1) ss += __shfl_down(ss, off);
  if ((t & 63) == 0) sred[t >> 6] = ss;
  __syncthreads();
  float tot = sred[0] + sred[1] + sred[2] + sred[3];
  float scale = rsqrtf(tot / (float)D_MODEL + EPSF);
  int h = t & 31, sl = t >> 5;
  float acc = 0.f;
  for (int k = sl * 256; k < sl * 256 + 256; k++)
    acc += sx[k] * w_in[(size_t)k * PROJ_DIM + (D_MODEL + CONV_DIMN) + h];
  red[sl][h] = acc;
  __syncthreads();
  if (t < 32) {
    float s = 0.f;
    #pragma unroll
    for (int i = 0; i < 8; i++) s += red[i][t];
    dtraw[(size_t)row * HEADS + t] = s * scale;
  }
}

// ---------------- bf16 MFMA GEMM: C[M,N] = A[M,K] @ BT[N,K]^T --------------
template<bool BF16OUT>
__global__ __launch_bounds__(256) void gemm_bt_k(const short* __restrict__ A,
                                                 const short* __restrict__ BT,
                                                 void* __restrict__ Cout,
                                                 int M, int N, int K) {
  __shared__ short sA[4096];
  __shared__ short sB[4096];
  int t = threadIdx.x;
  int lane = t & 63, w = t >> 6;
  int m0 = blockIdx.y * 128, n0 = blockIdx.x * 128;
  f32x4 acc[4][4] = {};
  int rS[2], ksS[2];
  #pragma unroll
  for (int ld = 0; ld < 2; ld++) {
    int c = w + ld * 4;
    int r = c * 16 + (lane >> 2);
    rS[ld] = r;
    ksS[ld] = (((lane & 3) ^ ((r >> 1) & 3))) * 8;
  }
  int q = lane >> 4, mr = lane & 15;
  int wm = (w & 1) * 64, wn = (w >> 1) * 64;
  int aoff[4], boff[4];
  #pragma unroll
  for (int i = 0; i < 4; i++) {
    int r = wm + i * 16 + mr;
    aoff[i] = r * 32 + (q ^ ((r >> 1) & 3)) * 8;
    int rn = wn + i * 16 + mr;
    boff[i] = rn * 32 + (q ^ ((rn >> 1) & 3)) * 8;
  }
  for (int k0 = 0; k0 < K; k0 += 32) {
    __syncthreads();
    #pragma unroll
    for (int ld = 0; ld < 2; ld++) {
      int c = w + ld * 4;
      gld16(A + (size_t)(m0 + rS[ld]) * K + k0 + ksS[ld], &sA[c * 512]);
      gld16(BT + (size_t)(n0 + rS[ld]) * K + k0 + ksS[ld], &sB[c * 512]);
    }
    __syncthreads();
    short8 af[4], bfr[4];
    #pragma unroll
    for (int i = 0; i < 4; i++) af[i] = *(const short8*)&sA[aoff[i]];
    #pragma unroll
    for (int i = 0; i < 4; i++) bfr[i] = *(const short8*)&sB[boff[i]];
    #pragma unroll
    for (int mi = 0; mi < 4; mi++)
      #pragma unroll
      for (int ni = 0; ni < 4; ni++)
        acc[mi][ni] = __builtin_amdgcn_mfma_f32_16x16x32_bf16(af[mi], bfr[ni], acc[mi][ni], 0, 0, 0);
  }
  int orow = (lane >> 4) * 4, ocol = lane & 15;
  #pragma unroll
  for (int mi = 0; mi < 4; mi++) {
    #pragma unroll
    for (int ni = 0; ni < 4; ni++) {
      int gn = n0 + wn + ni * 16 + ocol;
      if (gn >= N) continue;
      #pragma unroll
      for (int r = 0; r < 4; r++) {
        int gm = m0 + wm + mi * 16 + orow + r;
        if (BF16OUT) ((short*)Cout)[(size_t)gm * N + gn] = f2bf(acc[mi][ni][r]);
        else         ((float*)Cout)[(size_t)gm * N + gn] = acc[mi][ni][r];
      }
    }
  }
}

// ---------------- depthwise causal conv + bias + SiLU (bf16 in/out) --------
__global__ __launch_bounds__(256) void conv_silu_k(const short* __restrict__ projb,
                                                   const float* __restrict__ cw,
                                                   const float* __restrict__ cb,
                                                   short* __restrict__ out) {
  int idx = blockIdx.x * 256 + threadIdx.x;   // BL * CONV_DIM total
  int c = idx % CONV_DIMN;
  int bt = idx / CONV_DIMN;
  int t = bt % SEQL;
  int b = bt / SEQL;
  float acc = cb[c];
  #pragma unroll
  for (int k = 0; k < KCONV; k++) {
    int tt = t - (KCONV - 1) + k;
    if (tt >= 0)
      acc += b2f(projb[((size_t)(b * SEQL + tt)) * PROJB_W + D_MODEL + c]) * cw[c * KCONV + k];
  }
  out[idx] = f2bf(acc / (1.f + expf(-acc)));
}

// ---------------- dt softplus + per-chunk cumsum of A*dt -------------------
__global__ void dt_acs_k(const float* __restrict__ dtraw,
                         const float* __restrict__ dt_bias,
                         const float* __restrict__ A_log,
                         float* __restrict__ dtb, float* __restrict__ acsb) {
  int bc = blockIdx.x;
  int b = bc / NC, c = bc % NC;
  int l = threadIdx.x;  // 0..63
  int tok = c * CHUNK + l;
  size_t base = ((size_t)(b * SEQL + tok)) * HEADS;
  for (int h = 0; h < HEADS; h++) {
    float raw = dtraw[base + h] + dt_bias[h];
    float dt = raw > 20.f ? raw : log1pf(expf(raw));
    float adt = -expf(A_log[h]) * dt;
    float cs = adt;
    #pragma unroll
    for (int off = 1; off < 64; off <<= 1) {
      float v = __shfl_up(cs, off);
      if (l >= off) cs += v;
    }
    dtb[base + h] = dt;
    acsb[base + h] = cs;
  }
}

// ---------------- CB[b,c,l,s] = sum_n C(l,n)*B(s,n) -> bf16 ----------------
__global__ __launch_bounds__(256) void cb_k(const short* __restrict__ convb,
                                            short* __restrict__ CB) {
  int bc = blockIdx.x;
  int b = bc / NC, c = bc % NC;
  __shared__ float sC[64][65];
  __shared__ float sB[64][65];
  int t = threadIdx.x;
  int s = t & 63;
  int lb = (t >> 6) * 16;
  float acc[16] = {};
  size_t rowb = ((size_t)(b * SEQL + c * CHUNK)) * CONV_DIMN;
  for (int nt = 0; nt < 4; nt++) {
    __syncthreads();
    #pragma unroll
    for (int i = 0; i < 16; i++) {
      int e = t + 256 * i;
      int r = e >> 6, col = e & 63;
      sC[r][col] = b2f(convb[rowb + (size_t)r * CONV_DIMN + (D_MODEL + STATE) + nt * 64 + col]);
      sB[r][col] = b2f(convb[rowb + (size_t)r * CONV_DIMN + D_MODEL + nt * 64 + col]);
    }
    __syncthreads();
    for (int n = 0; n < 64; n++) {
      float bv = sB[s][n];
      #pragma unroll
      for (int j = 0; j < 16; j++) acc[j] += sC[lb + j][n] * bv;
    }
  }
  size_t ob = ((size_t)bc) * 64 * 64;
  #pragma unroll
  for (int j = 0; j < 16; j++) CB[ob + (size_t)(lb + j) * 64 + s] = f2bf(acc[j]);
}

// ---------------- chunk states via MFMA: G[p][n] = sum_l xsw(l,p)*B(l,n) ---
// per-batch: grid c*HEADS+h (1024). XOR chunk swizzle kills 32-way write bc.
__global__ __launch_bounds__(256) void chunk_states_k(const short* __restrict__ convb,
                                                      const float* __restrict__ dtb,
                                                      const float* __restrict__ acsb,
                                                      int b, short* __restrict__ G) {
  int blk = blockIdx.x;            // c*HEADS + h
  int h = blk & 31, c = blk >> 5;
  __shared__ __align__(16) short sXT[64][72];   // [p][l-swz] = bf16(xs(l,p)*wt(l))
  __shared__ __align__(16) short sBT[256][72];  // [n][l-swz] = B(l,n)
  __shared__ float swt[64];
  int t = threadIdx.x;
  size_t rowb = ((size_t)(b * SEQL + c * CHUNK)) * CONV_DIMN;
  size_t ab = ((size_t)(b * SEQL + c * CHUNK)) * HEADS;
  if (t < 64) {
    float a = acsb[ab + (size_t)t * HEADS + h];
    float alast = acsb[ab + (size_t)63 * HEADS + h];
    swt[t] = expf(alast - a) * dtb[ab + (size_t)t * HEADS + h];
  }
  __syncthreads();
  #pragma unroll
  for (int i = 0; i < 4; i++) {
    int e = t + 256 * i;
    int l = e >> 4, p4 = (e & 15) * 4;
    short4v v = *(const short4v*)&convb[rowb + (size_t)l * CONV_DIMN + h * HEAD_DIM + p4];
    float wt = swt[l];
    short vv[4] = {v.x, v.y, v.z, v.w};
    #pragma unroll
    for (int j = 0; j < 4; j++) {
      int p = p4 + j;
      sXT[p][((((l >> 3) ^ ((p >> 2) & 7)) << 3) | (l & 7))] = f2bf(b2f(vv[j]) * wt);
    }
  }
  #pragma unroll
  for (int i = 0; i < 16; i++) {
    int e = t + 256 * i;
    int l = e >> 6, n4 = (e & 63) * 4;
    short4v v = *(const short4v*)&convb[rowb + (size_t)l * CONV_DIMN + D_MODEL + n4];
    short vv[4] = {v.x, v.y, v.z, v.w};
    #pragma unroll
    for (int j = 0; j < 4; j++) {
      int n = n4 + j;
      sBT[n][((((l >> 3) ^ ((n >> 2) & 7)) << 3) | (l & 7))] = vv[j];
    }
  }
  __syncthreads();
  int lane = t & 63, w = t >> 6;
  int mr = lane & 15, q = lane >> 4;
  f32x4 acc[4][4] = {};
  #pragma unroll
  for (int ks = 0; ks < 2; ks++) {
    short8 af[4], bfr[4];
    #pragma unroll
    for (int mi = 0; mi < 4; mi++) {
      int p = mi * 16 + mr;
      af[mi] = *(const short8*)&sXT[p][(((ks * 4 + q) ^ ((p >> 2) & 7)) << 3)];
    }
    #pragma unroll
    for (int ni = 0; ni < 4; ni++) {
      int n = w * 64 + ni * 16 + mr;
      bfr[ni] = *(const short8*)&sBT[n][(((ks * 4 + q) ^ ((n >> 2) & 7)) << 3)];
    }
    #pragma unroll
    for (int mi = 0; mi < 4; mi++)
      #pragma unroll
      for (int ni = 0; ni < 4; ni++)
        acc[mi][ni] = __builtin_amdgcn_mfma_f32_16x16x32_bf16(af[mi], bfr[ni], acc[mi][ni], 0, 0, 0);
  }
  size_t gb = (size_t)blk * (64 * 256);
  #pragma unroll
  for (int mi = 0; mi < 4; mi++)
    #pragma unroll
    for (int ni = 0; ni < 4; ni++)
      #pragma unroll
      for (int r = 0; r < 4; r++)
        G[gb + (size_t)(mi * 16 + q * 4 + r) * 256 + w * 64 + ni * 16 + mr] = f2bf(acc[mi][ni][r]);
}

// ---------------- sequential chunk recursion (per batch), in-place ---------
__global__ __launch_bounds__(256) void scan_states_k(short* __restrict__ G,
                                                     const float* __restrict__ acsb,
                                                     int b) {
  int gid = blockIdx.x * 256 + threadIdx.x;   // 2^18 threads
  int np = gid & 127;
  int p  = (gid >> 7) & 63;
  int h  = gid >> 13;                          // 0..31
  float S0 = 0.f, S1 = 0.f;
  for (int c = 0; c < NC; c++) {
    size_t base = (((size_t)(c * HEADS + h) * 64) + p) * 256 + np * 2;
    unsigned u = *(const unsigned*)&G[base];
    float g0 = b2f((short)(u & 0xffff));
    float g1 = b2f((short)(u >> 16));
    unsigned wv = (unsigned)(unsigned short)f2bf(S0) | ((unsigned)(unsigned short)f2bf(S1) << 16);
    *(unsigned*)&G[base] = wv;
    float dec = expf(acsb[((size_t)(b * SEQL + c * CHUNK + 63)) * HEADS + h]);
    S0 = S0 * dec + g0;
    S1 = S1 * dec + g1;
  }
}

// ---------------- fused Y = Ydiag + ea_l*Yoff + D*xs (per batch) -----------
// MFMA1: M(l,s) @ xs^T  (M staged w/ mask+exp, xs^T staged swizzled)
// MFMA2: C(l,n) @ S(p,n)^T direct from global (row factor ea_l in epilogue)
__global__ __launch_bounds__(256) void y_fused_k(const short* __restrict__ convb,
                                                 const short* __restrict__ CBb,
                                                 const short* __restrict__ G,
                                                 const float* __restrict__ dtb,
                                                 const float* __restrict__ acsb,
                                                 const float* __restrict__ D_skip,
                                                 int b, float* __restrict__ Y) {
  int blk = blockIdx.x;            // c*HEADS + h
  int h = blk & 31, c = blk >> 5;
  __shared__ __align__(16) short sM[64][72];    // M(l,s) bf16, plain cols
  __shared__ __align__(16) short sXT[64][72];   // [p][l-swz] = xs(l,p)
  __shared__ float sacs[64], sdt[64], sea[64];
  int t = threadIdx.x;
  int lane = t & 63, w = t >> 6;
  size_t rowb = ((size_t)(b * SEQL + c * CHUNK)) * CONV_DIMN;
  size_t ab = ((size_t)(b * SEQL + c * CHUNK)) * HEADS;
  size_t cbbase = ((size_t)(b * NC + c)) * 64 * 64;
  if (t < 64) {
    float a = acsb[ab + (size_t)t * HEADS + h];
    sacs[t] = a;
    sea[t] = expf(a);
    sdt[t] = dtb[ab + (size_t)t * HEADS + h];
  }
  __syncthreads();
  // stage M(l,s) = CB * exp(acs_l - acs_s) * dt_s * [s<=l]
  #pragma unroll
  for (int i = 0; i < 16; i++) {
    int e = t + 256 * i;
    int r = e >> 6, col = e & 63;
    float m = 0.f;
    if (col <= r)
      m = b2f(CBb[cbbase + (size_t)r * 64 + col]) * expf(sacs[r] - sacs[col]) * sdt[col];
    sM[r][col] = f2bf(m);
  }
  // stage xs^T (raw)
  #pragma unroll
  for (int i = 0; i < 4; i++) {
    int e = t + 256 * i;
    int l = e >> 4, p4 = (e & 15) * 4;
    short4v v = *(const short4v*)&convb[rowb + (size_t)l * CONV_DIMN + h * HEAD_DIM + p4];
    short vv[4] = {v.x, v.y, v.z, v.w};
    #pragma unroll
    for (int j = 0; j < 4; j++) {
      int p = p4 + j;
      sXT[p][((((l >> 3) ^ ((p >> 2) & 7)) << 3) | (l & 7))] = vv[j];
    }
  }
  __syncthreads();
  int mr = lane & 15, q = lane >> 4;
  int wm = (w & 1) * 32, wn = (w >> 1) * 32;
  f32x4 acc1[2][2] = {}, acc2[2][2] = {};
  // MFMA1: Ydiag
  #pragma unroll
  for (int ks = 0; ks < 2; ks++) {
    short8 af[2], bfr[2];
    #pragma unroll
    for (int mi = 0; mi < 2; mi++)
      af[mi] = *(const short8*)&sM[wm + mi * 16 + mr][ks * 32 + q * 8];
    #pragma unroll
    for (int ni = 0; ni < 2; ni++) {
      int p = wn + ni * 16 + mr;
      bfr[ni] = *(const short8*)&sXT[p][(((ks * 4 + q) ^ ((p >> 2) & 7)) << 3)];
    }
    #pragma unroll
    for (int mi = 0; mi < 2; mi++)
      #pragma unroll
      for (int ni = 0; ni < 2; ni++)
        acc1[mi][ni] = __builtin_amdgcn_mfma_f32_16x16x32_bf16(af[mi], bfr[ni], acc1[mi][ni], 0, 0, 0);
  }
  // MFMA2: Yoff/ea -- operands direct from global (raw C rows, S rows)
  const short* Crow = convb + rowb + (D_MODEL + STATE);
  size_t gbase = (size_t)blk * (64 * 256);
  #pragma unroll
  for (int st = 0; st < 8; st++) {
    short8 af[2], bfr[2];
    #pragma unroll
    for (int mi = 0; mi < 2; mi++) {
      int l = wm + mi * 16 + mr;
      af[mi] = *(const short8*)&Crow[(size_t)l * CONV_DIMN + st * 32 + q * 8];
    }
    #pragma unroll
    for (int ni = 0; ni < 2; ni++) {
      int p = wn + ni * 16 + mr;
      bfr[ni] = *(const short8*)&G[gbase + (size_t)p * 256 + st * 32 + q * 8];
    }
    #pragma unroll
    for (int mi = 0; mi < 2; mi++)
      #pragma unroll
      for (int ni = 0; ni < 2; ni++)
        acc2[mi][ni] = __builtin_amdgcn_mfma_f32_16x16x32_bf16(af[mi], bfr[ni], acc2[mi][ni], 0, 0, 0);
  }
  // epilogue
  float dsk = D_skip[h];
  size_t ybase = ((size_t)(b * SEQL + c * CHUNK)) * D_MODEL + h * HEAD_DIM;
  #pragma unroll
  for (int mi = 0; mi < 2; mi++)
    #pragma unroll
    for (int ni = 0; ni < 2; ni++) {
      int p = wn + ni * 16 + mr;
      #pragma unroll
      for (int r = 0; r < 4; r++) {
        int l = wm + mi * 16 + q * 4 + r;
        float xsv = b2f(sXT[p][((((l >> 3) ^ ((p >> 2) & 7)) << 3) | (l & 7))]);
        Y[ybase + (size_t)l * D_MODEL + p] =
            acc1[mi][ni][r] + sea[l] * acc2[mi][ni][r] + dsk * xsv;
      }
    }
}

// ---------------- gated RMSNorm -> bf16 (z from projb) ---------------------
__global__ __launch_bounds__(256) void gated_norm_bf16_k(const float* __restrict__ Y,
                                                         const short* __restrict__ projb,
                                                         const float* __restrict__ gw,
                                                         short* __restrict__ out) {
  int row = blockIdx.x;
  int t = threadIdx.x;
  const float4* y4 = (const float4*)(Y + (size_t)row * D_MODEL);
  float4 ya = y4[2 * t], yb = y4[2 * t + 1];
  short zt[8];
  *(int4*)zt = *(const int4*)(projb + (size_t)row * PROJB_W + t * 8);
  float g[8];
  float yv[8] = {ya.x, ya.y, ya.z, ya.w, yb.x, yb.y, yb.z, yb.w};
  float ss = 0.f;
  #pragma unroll
  for (int i = 0; i < 8; i++) {
    float z = b2f(zt[i]);
    g[i] = yv[i] * (z / (1.f + expf(-z)));
    ss += g[i] * g[i];
  }
  #pragma unroll
  for (int off = 32; off > 0; off >>= 1) ss += __shfl_down(ss, off);
  __shared__ float ws_[4];
  if ((t & 63) == 0) ws_[t >> 6] = ss;
  __syncthreads();
  float tot = ws_[0] + ws_[1] + ws_[2] + ws_[3];
  float scale = rsqrtf(tot / (float)D_MODEL + EPSF);
  const float4* g4 = (const float4*)gw;
  float4 wa = g4[2 * t], wb = g4[2 * t + 1];
  float wv[8] = {wa.x, wa.y, wa.z, wa.w, wb.x, wb.y, wb.z, wb.w};
  short tmp[8];
  #pragma unroll
  for (int i = 0; i < 8; i++) tmp[i] = f2bf(g[i] * scale * wv[i]);
  *(int4*)(out + (size_t)row * D_MODEL + t * 8) = *(int4*)tmp;
}

extern "C" void kernel_launch(void* const* d_in, const int* in_sizes, int n_in,
                              void* d_out, int out_size, void* d_ws, size_t ws_size,
                              hipStream_t stream) {
  const float* x       = (const float*)d_in[0];
  const float* norm_w  = (const float*)d_in[1];
  const float* w_in    = (const float*)d_in[2];
  const float* conv_w  = (const float*)d_in[3];
  const float* conv_b  = (const float*)d_in[4];
  const float* dt_bias = (const float*)d_in[5];
  const float* A_log   = (const float*)d_in[6];
  const float* D_skip  = (const float*)d_in[7];
  const float* gnorm_w = (const float*)d_in[8];
  const float* w_out   = (const float*)d_in[9];
  const float* wo_w    = (const float*)d_in[10];
  float* out = (float*)d_out;

  // workspace (float units), total 36,700,160 fu = 140 MiB
  float* ws    = (float*)d_ws;
  short* xnb   = (short*)ws;                 // [0 .. 4,194,304 fu)  bf16 4096x2048
  short* w_inT = (short*)(ws + 4194304);     // 4,718,592 fu         bf16 4608x2048
  short* projb = (short*)(ws + 8912896);     // 9,437,184 fu         bf16 4096x4608
  short* convb = (short*)(ws + 18350080);    // 5,242,880 fu         bf16 4096x2560
  float* dtraw = ws + 23592960;              // 131,072
  float* dtb   = ws + 23724032;              // 131,072
  float* acsb  = ws + 23855104;              // 131,072
  short* CBb   = (short*)(ws + 23986176);    // 131,072 fu           bf16 64x64x64
  float* Yb    = ws + 24117248;              // 8,388,608
  short* w_outT= (short*)(ws + 32505856);    // 2,097,152 fu
  short* wo_wT = (short*)(ws + 34603008);    // 2,097,152 fu
  short* G     = (short*)ws;                 // per-batch 8,388,608 fu over xnb+w_inT(dead)
  short* Yg    = convb;                      // overlays convb after y_fused
  short* t1b   = (short*)ws;                 // overlays G region after y_fused

  rmsnorm_bf16_k<<<BL, 256, 0, stream>>>(x, norm_w, xnb);
  transpose_bf16_k<<<dim3(PROJB_W / 32, D_MODEL / 32), 256, 0, stream>>>(w_in, w_inT, D_MODEL, PROJB_W, PROJ_DIM);
  transpose_bf16_k<<<dim3(D_MODEL / 32, D_MODEL / 32), 256, 0, stream>>>(w_out, w_outT, D_MODEL, D_MODEL, D_MODEL);
  transpose_bf16_k<<<dim3(D_MODEL / 32, D_MODEL / 32), 256, 0, stream>>>(wo_w, wo_wT, D_MODEL, D_MODEL, D_MODEL);
  dt_gemm_k<<<BL, 256, 0, stream>>>(x, norm_w, w_in, dtraw);
  gemm_bt_k<true><<<dim3(PROJB_W / 128, BL / 128), 256, 0, stream>>>(xnb, w_inT, projb, BL, PROJB_W, D_MODEL);
  conv_silu_k<<<(BL * CONV_DIMN) / 256, 256, 0, stream>>>(projb, conv_w, conv_b, convb);
  dt_acs_k<<<BATCHN * NC, 64, 0, stream>>>(dtraw, dt_bias, A_log, dtb, acsb);
  cb_k<<<BATCHN * NC, 256, 0, stream>>>(convb, CBb);
  for (int b = 0; b < BATCHN; b++) {
    chunk_states_k<<<NC * HEADS, 256, 0, stream>>>(convb, dtb, acsb, b, G);
    scan_states_k<<<1024, 256, 0, stream>>>(G, acsb, b);
    y_fused_k<<<NC * HEADS, 256, 0, stream>>>(convb, CBb, G, dtb, acsb, D_skip, b, Yb);
  }
  gated_norm_bf16_k<<<BL, 256, 0, stream>>>(Yb, projb, gnorm_w, Yg);
  gemm_bt_k<true><<<dim3(D_MODEL / 128, BL / 128), 256, 0, stream>>>(Yg, w_outT, t1b, BL, D_MODEL, D_MODEL);
  gemm_bt_k<false><<<dim3(D_MODEL / 128, BL / 128), 256, 0, stream>>>(t1b, wo_wT, out, BL, D_MODEL, D_MODEL);
}